// Round 1
// 1626.413 us; speedup vs baseline: 1.7961x; 1.7961x over previous
//
#include <hip/hip_runtime.h>

#define BT 6272      // B*T = 32*196
#define TT 196
#define DM 512
#define FFD 2048
#define NE 8
#define ABUF 3211264 // activation buffer elems (6272*512)
#define SLOTS 12544  // BT*2 expert slots

typedef float f32x4 __attribute__((ext_vector_type(4)));
typedef __bf16 bf16x8 __attribute__((ext_vector_type(8)));

__device__ __forceinline__ ushort f2bf(float f){
  union { float f; unsigned u; } v; v.f = f;
  unsigned u = v.u;
  u += 0x7fffu + ((u >> 16) & 1u);   // RNE
  return (ushort)(u >> 16);
}

// ---------------- patchify: x[B,1,224,224] f32 -> patches[BT,256] f32 ----------------
__global__ void patchify_k(const float* __restrict__ x, float* __restrict__ out){
  int bt = blockIdx.x;
  int t = bt % TT, b = bt / TT;
  int pd = threadIdx.x;
  int g1 = t / 14, g2 = t % 14, p1 = pd >> 4, p2 = pd & 15;
  int src = (b*224 + g1*16 + p1)*224 + g2*16 + p2;
  out[(size_t)bt*256 + pd] = x[src];
}

// ---------------- posenc[196,512] f32 ----------------
__global__ void posenc_k(float* __restrict__ pe){
  int t = blockIdx.x, c = threadIdx.x;
  int m2 = c & ~1;
  double ang = (double)t * pow(10000.0, -(double)m2 / 512.0);
  double vv = (c & 1) ? cos(ang) : sin(ang);
  pe[t*DM + c] = (float)vv;
}

// ---------------- 128x128 fp32 GEMM, 256 thr, 8x8/thread, reg prefetch ----------------
__global__ __launch_bounds__(256)
void gemm128(const float* __restrict__ A, const float* __restrict__ B,
             float* __restrict__ C, const float* __restrict__ bias,
             const float* __restrict__ pe, float* __restrict__ mirror,
             int N, int K)
{
  __shared__ float As[16][132];
  __shared__ float Bs[16][132];
  int tid = threadIdx.x;
  int row0 = blockIdx.y << 7, col0 = blockIdx.x << 7;
  int ar = tid >> 1, ak = (tid & 1) << 3;
  int bk = tid >> 4, bn = (tid & 15) << 3;
  int m0 = (tid >> 4) << 3, n0 = (tid & 15) << 3;
  const float* Ap = A + (size_t)(row0 + ar) * K + ak;
  const float* Bp = B + (size_t)bk * N + col0 + bn;
  float4 a0 = *(const float4*)(Ap);
  float4 a1 = *(const float4*)(Ap + 4);
  float4 b0 = *(const float4*)(Bp);
  float4 b1 = *(const float4*)(Bp + 4);
  float acc[8][8] = {};
  for (int k0 = 0; k0 < K; k0 += 16){
    __syncthreads();
    As[ak+0][ar]=a0.x; As[ak+1][ar]=a0.y; As[ak+2][ar]=a0.z; As[ak+3][ar]=a0.w;
    As[ak+4][ar]=a1.x; As[ak+5][ar]=a1.y; As[ak+6][ar]=a1.z; As[ak+7][ar]=a1.w;
    *(float4*)&Bs[bk][bn]   = b0;
    *(float4*)&Bs[bk][bn+4] = b1;
    __syncthreads();
    if (k0 + 16 < K){
      a0 = *(const float4*)(Ap + k0 + 16);
      a1 = *(const float4*)(Ap + k0 + 20);
      b0 = *(const float4*)(Bp + (size_t)(k0+16)*N);
      b1 = *(const float4*)(Bp + (size_t)(k0+16)*N + 4);
    }
    #pragma unroll
    for (int kk = 0; kk < 16; ++kk){
      float4 x0 = *(const float4*)&As[kk][m0];
      float4 x1 = *(const float4*)&As[kk][m0+4];
      float4 y0 = *(const float4*)&Bs[kk][n0];
      float4 y1 = *(const float4*)&Bs[kk][n0+4];
      float xa[8] = {x0.x,x0.y,x0.z,x0.w,x1.x,x1.y,x1.z,x1.w};
      float yb[8] = {y0.x,y0.y,y0.z,y0.w,y1.x,y1.y,y1.z,y1.w};
      #pragma unroll
      for (int i = 0; i < 8; ++i)
        #pragma unroll
        for (int j = 0; j < 8; ++j)
          acc[i][j] += xa[i]*yb[j];
    }
  }
  float badd[8] = {};
  if (bias){
    float4 v0 = *(const float4*)(bias + col0 + n0);
    float4 v1 = *(const float4*)(bias + col0 + n0 + 4);
    badd[0]=v0.x; badd[1]=v0.y; badd[2]=v0.z; badd[3]=v0.w;
    badd[4]=v1.x; badd[5]=v1.y; badd[6]=v1.z; badd[7]=v1.w;
  }
  #pragma unroll
  for (int i = 0; i < 8; ++i){
    int gr = row0 + m0 + i;
    float r[8];
    #pragma unroll
    for (int j = 0; j < 8; ++j) r[j] = acc[i][j] + badd[j];
    if (pe){
      const float* pv = pe + (size_t)(gr % TT)*DM + col0 + n0;
      #pragma unroll
      for (int j = 0; j < 8; ++j) r[j] += pv[j];
    }
    float* cp = C + (size_t)gr*N + col0 + n0;
    *(float4*)cp       = make_float4(r[0],r[1],r[2],r[3]);
    *(float4*)(cp + 4) = make_float4(r[4],r[5],r[6],r[7]);
    if (mirror){
      float* mp = mirror + (size_t)gr*N + col0 + n0;
      *(float4*)mp       = make_float4(r[0],r[1],r[2],r[3]);
      *(float4*)(mp + 4) = make_float4(r[4],r[5],r[6],r[7]);
    }
  }
}

// ---------------- old 64x64 GEMM (kept for the tiny cls matmul, M=32) ----------------
__global__ __launch_bounds__(256)
void gemm_f32(const float* __restrict__ A, const float* __restrict__ Bw,
              float* __restrict__ C, const float* __restrict__ bias,
              float* __restrict__ obf, int M, int N, int K)
{
  __shared__ float As[16][68];
  __shared__ float Bs[16][68];
  int tid = threadIdx.x;
  int row0 = blockIdx.y << 6, col0 = blockIdx.x << 6;
  int ar = tid >> 2, ak = (tid & 3) << 2;
  int bk = tid >> 4, bn = (tid & 15) << 2;
  int n0 = (tid & 15) << 2, m0 = (tid >> 4) << 2;
  float acc[4][4] = {};
  bool arow_ok = (row0 + ar) < M;
  const float* Aldg = A + (size_t)(row0 + ar) * K + ak;
  const float* Bldg = Bw + (size_t)bk * N + col0 + bn;
  for (int k0 = 0; k0 < K; k0 += 16){
    float4 av = make_float4(0.f,0.f,0.f,0.f);
    if (arow_ok) av = *(const float4*)(Aldg + k0);
    float4 bv = *(const float4*)(Bldg + (size_t)k0 * N);
    __syncthreads();
    As[ak+0][ar]=av.x; As[ak+1][ar]=av.y; As[ak+2][ar]=av.z; As[ak+3][ar]=av.w;
    *(float4*)&Bs[bk][bn] = bv;
    __syncthreads();
    #pragma unroll
    for (int kk = 0; kk < 16; ++kk){
      float4 a = *(const float4*)&As[kk][m0];
      float4 b = *(const float4*)&Bs[kk][n0];
      float aa[4] = {a.x,a.y,a.z,a.w};
      float bb[4] = {b.x,b.y,b.z,b.w};
      #pragma unroll
      for (int i = 0; i < 4; ++i)
        #pragma unroll
        for (int j = 0; j < 4; ++j)
          acc[i][j] += aa[i]*bb[j];
    }
  }
  float4 badd = make_float4(0.f,0.f,0.f,0.f);
  if (bias) badd = *(const float4*)(bias + col0 + n0);
  #pragma unroll
  for (int i = 0; i < 4; ++i){
    int gr = row0 + m0 + i;
    if (gr < M){
      float4 r = make_float4(acc[i][0]+badd.x, acc[i][1]+badd.y, acc[i][2]+badd.z, acc[i][3]+badd.w);
      *(float4*)(C + (size_t)gr*N + col0 + n0) = r;
      if (obf) *(float4*)(obf + (size_t)gr*N + col0 + n0) = r;
    }
  }
}

// ---------------- flash-style causal attention (unchanged) ----------------
__global__ __launch_bounds__(256)
void fattn_k(const float* q, const float* __restrict__ k,
             const float* __restrict__ v, float* o)
{
  __shared__ float Qt[64][68];
  __shared__ float KP[64][68];
  __shared__ float Vs[64][68];
  int qt = blockIdx.x, bh = blockIdx.y;
  int b = bh >> 3, h = bh & 7;
  size_t base = (size_t)b * TT * DM + h * 64;
  int tid = threadIdx.x;
  int ty = tid >> 4, tx = tid & 15;
  int m0 = ty << 2, n0 = tx << 2;
  {
    int r = tid >> 2, dd = (tid & 3) << 4;
    int qrow = qt*64 + r;
    const float* qp = q + base + (size_t)(qrow < TT ? qrow : TT-1) * DM;
    #pragma unroll
    for (int u = 0; u < 4; ++u){
      float4 t4 = *(const float4*)(qp + dd + u*4);
      Qt[dd+u*4+0][r]=t4.x; Qt[dd+u*4+1][r]=t4.y; Qt[dd+u*4+2][r]=t4.z; Qt[dd+u*4+3][r]=t4.w;
    }
  }
  float o_acc[4][4] = {};
  float m_i[4], l_i[4];
  #pragma unroll
  for (int i = 0; i < 4; ++i){ m_i[i] = -3e38f; l_i[i] = 0.f; }
  int ktiles = qt + 1;
  for (int kt = 0; kt < ktiles; ++kt){
    __syncthreads();
    {
      int r = tid >> 2, dd = (tid & 3) << 4;
      int jrow = kt*64 + r;
      int jc = jrow < TT ? jrow : TT-1;
      const float* kp = k + base + (size_t)jc * DM;
      const float* vp = v + base + (size_t)jc * DM;
      #pragma unroll
      for (int u = 0; u < 4; ++u){
        float4 t4 = *(const float4*)(kp + dd + u*4);
        KP[dd+u*4+0][r]=t4.x; KP[dd+u*4+1][r]=t4.y; KP[dd+u*4+2][r]=t4.z; KP[dd+u*4+3][r]=t4.w;
        *(float4*)&Vs[r][dd + u*4] = *(const float4*)(vp + dd + u*4);
      }
    }
    __syncthreads();
    float s[4][4] = {};
    #pragma unroll 8
    for (int d = 0; d < 64; ++d){
      float4 a = *(const float4*)&Qt[d][m0];
      float4 bb = *(const float4*)&KP[d][n0];
      float xa[4] = {a.x,a.y,a.z,a.w};
      float yb[4] = {bb.x,bb.y,bb.z,bb.w};
      #pragma unroll
      for (int i = 0; i < 4; ++i)
        #pragma unroll
        for (int j = 0; j < 4; ++j)
          s[i][j] += xa[i]*yb[j];
    }
    int qrow0 = qt*64 + m0, jcol0 = kt*64 + n0;
    #pragma unroll
    for (int i = 0; i < 4; ++i)
      #pragma unroll
      for (int j = 0; j < 4; ++j){
        int jj = jcol0 + j;
        s[i][j] = (jj <= qrow0 + i && jj < TT) ? s[i][j]*0.125f : -3e38f;
      }
    float p[4][4];
    #pragma unroll
    for (int i = 0; i < 4; ++i){
      float mx = fmaxf(fmaxf(s[i][0],s[i][1]), fmaxf(s[i][2],s[i][3]));
      #pragma unroll
      for (int off = 1; off < 16; off <<= 1) mx = fmaxf(mx, __shfl_xor(mx, off, 64));
      float mnew = fmaxf(m_i[i], mx);
      float al = expf(m_i[i] - mnew);
      l_i[i] *= al;
      #pragma unroll
      for (int c = 0; c < 4; ++c) o_acc[i][c] *= al;
      float ps = 0.f;
      #pragma unroll
      for (int j = 0; j < 4; ++j){ p[i][j] = expf(s[i][j] - mnew); ps += p[i][j]; }
      #pragma unroll
      for (int off = 1; off < 16; off <<= 1) ps += __shfl_xor(ps, off, 64);
      l_i[i] += ps;
      m_i[i] = mnew;
    }
    __syncthreads();
    #pragma unroll
    for (int i = 0; i < 4; ++i)
      #pragma unroll
      for (int j = 0; j < 4; ++j)
        KP[n0 + j][m0 + i] = p[i][j];
    __syncthreads();
    #pragma unroll 8
    for (int jj = 0; jj < 64; ++jj){
      float4 a = *(const float4*)&KP[jj][m0];
      float4 bb = *(const float4*)&Vs[jj][n0];
      float xa[4] = {a.x,a.y,a.z,a.w};
      float yb[4] = {bb.x,bb.y,bb.z,bb.w};
      #pragma unroll
      for (int i = 0; i < 4; ++i)
        #pragma unroll
        for (int c = 0; c < 4; ++c)
          o_acc[i][c] += xa[i]*yb[c];
    }
  }
  #pragma unroll
  for (int i = 0; i < 4; ++i){
    int qrow = qt*64 + m0 + i;
    if (qrow < TT){
      float inv = 1.f / l_i[i];
      float4 r = make_float4(o_acc[i][0]*inv, o_acc[i][1]*inv, o_acc[i][2]*inv, o_acc[i][3]*inv);
      *(float4*)(o + base + (size_t)qrow*DM + n0) = r;
    }
  }
}

// ---------------- router: LDS-staged transposed weights, no atomics ----------------
__global__ __launch_bounds__(256)
void router2_k(const float* __restrict__ X, const float* __restrict__ rtW, const float* __restrict__ rtb,
               const float* __restrict__ rnW, const float* __restrict__ rnb, const float* __restrict__ nz,
               int* __restrict__ tok_e, float* __restrict__ tok_g)
{
  __shared__ float Wt[8*513];
  __shared__ float Wn[8*513];
  int tid = threadIdx.x;
  for (int i = tid*4; i < DM*8; i += 1024){
    float4 t = *(const float4*)(rtW + i);
    float4 n = *(const float4*)(rnW + i);
    int d = i >> 3, e = i & 7;
    Wt[(e+0)*513 + d] = t.x; Wt[(e+1)*513 + d] = t.y; Wt[(e+2)*513 + d] = t.z; Wt[(e+3)*513 + d] = t.w;
    Wn[(e+0)*513 + d] = n.x; Wn[(e+1)*513 + d] = n.y; Wn[(e+2)*513 + d] = n.z; Wn[(e+3)*513 + d] = n.w;
  }
  __syncthreads();
  int w = tid >> 6, lane = tid & 63;
  int t = (blockIdx.x << 2) + w;
  const float* xr = X + (size_t)t * DM;
  float at[8] = {}, an[8] = {};
  #pragma unroll
  for (int u = 0; u < 8; ++u){
    int d = (u<<6) + lane;
    float xv = xr[d];
    #pragma unroll
    for (int e = 0; e < 8; ++e){
      at[e] += xv * Wt[e*513 + d];
      an[e] += xv * Wn[e*513 + d];
    }
  }
  #pragma unroll
  for (int off = 32; off; off >>= 1){
    #pragma unroll
    for (int e = 0; e < 8; ++e){
      at[e] += __shfl_xor(at[e], off, 64);
      an[e] += __shfl_xor(an[e], off, 64);
    }
  }
  if (lane == 0){
    float ns[8];
    #pragma unroll
    for (int e = 0; e < 8; ++e){
      float lt = at[e] + rtb[e];
      float ln_ = an[e] + rnb[e];
      float sp = (ln_ > 0.f) ? (ln_ + log1pf(expf(-ln_))) : log1pf(expf(ln_));
      ns[e] = lt + nz[(size_t)t*8 + e] * sp;
    }
    int i1 = 0; float n1 = ns[0];
    #pragma unroll
    for (int e = 1; e < 8; ++e) if (ns[e] > n1){ n1 = ns[e]; i1 = e; }
    int i2 = -1; float n2 = -3e38f;
    #pragma unroll
    for (int e = 0; e < 8; ++e) if (e != i1 && ns[e] > n2){ n2 = ns[e]; i2 = e; }
    float ex = expf(n2 - n1);
    float inv = 1.f / (1.f + ex);
    tok_e[t*2]   = i1; tok_g[t*2]   = inv;
    tok_e[t*2+1] = i2; tok_g[t*2+1] = ex * inv;
  }
}

// ---------------- single-block histogram + prefix + slot assignment ----------------
__global__ __launch_bounds__(1024)
void route_assign_k(const int* __restrict__ tok_e, int* __restrict__ offs_g,
                    int* __restrict__ idx_c, int* __restrict__ tok_slot)
{
  __shared__ int hist[NE];
  __shared__ int cur[NE];
  int tid = threadIdx.x;
  if (tid < NE) hist[tid] = 0;
  __syncthreads();
  for (int i = tid; i < BT*2; i += 1024) atomicAdd(&hist[tok_e[i]], 1);
  __syncthreads();
  if (tid == 0){
    int s = 0;
    for (int e = 0; e < NE; ++e){ offs_g[e] = s; cur[e] = s; s += hist[e]; }
    offs_g[NE] = s;
  }
  __syncthreads();
  for (int i = tid; i < BT*2; i += 1024){
    int e = tok_e[i];
    int p = atomicAdd(&cur[e], 1);
    idx_c[p] = i >> 1;
    tok_slot[i] = p;
  }
}

// ---------------- transpose + f32->bf16 convert: src[R][C] -> dst[C][R], per expert ----------------
__global__ __launch_bounds__(256)
void transconv_k(const float* __restrict__ src, ushort* __restrict__ dst, int R, int C){
  __shared__ float t[32][33];
  int e = blockIdx.z;
  src += (size_t)e * R * C;
  dst += (size_t)e * R * C;
  int c0 = blockIdx.x << 5, r0 = blockIdx.y << 5;
  int tx = threadIdx.x & 31, ty = threadIdx.x >> 5;
  #pragma unroll
  for (int i = 0; i < 32; i += 8)
    t[ty+i][tx] = src[(size_t)(r0+ty+i)*C + c0 + tx];
  __syncthreads();
  #pragma unroll
  for (int i = 0; i < 32; i += 8)
    dst[(size_t)(c0+ty+i)*R + r0 + tx] = f2bf(t[tx][ty+i]);
}

// ---------------- gather routed rows + convert to bf16: Xg[slot][512] ----------------
__global__ void gatherconv_k(const float* __restrict__ X, const int* __restrict__ idx,
                             ushort* __restrict__ Xg){
  int s = blockIdx.x;
  const float* xp = X + (size_t)idx[s] * DM;
  ushort* op = Xg + (size_t)s * DM;
  int i = threadIdx.x * 2;
  float2 v = *(const float2*)(xp + i);
  ushort2 o; o.x = f2bf(v.x); o.y = f2bf(v.y);
  *(ushort2*)(op + i) = o;
}

// ---------------- MoE expert GEMM, bf16 MFMA 16x16x32, 128x128 tile, 4 waves ----------------
// MODE 0: H1b[slot][out_ld] = bf16(relu(Xg[slot] @ WiT[e]^T + bi))   (A=Xg, B=WiT n-major)
// MODE 1: Ye[slot][out_ld]  = H1b[slot] @ WoT[e]^T + bo (or += if accum)
// Both operands k-contiguous in memory; K == kld (A row stride).
template<int MODE>
__global__ __launch_bounds__(256)
void moe_mfma(const ushort* __restrict__ A, const ushort* __restrict__ Bt,
              const float* __restrict__ bias, const int* __restrict__ offs,
              void* __restrict__ Out, int kld, int ldb, int out_ld, int accum)
{
  int e = blockIdx.z;
  int base = offs[e], cnt = offs[e+1] - base;
  int row0 = blockIdx.y << 7;
  if (row0 >= cnt) return;
  int col0 = blockIdx.x << 7;
  __shared__ ushort As[128][40];   // row-pad to 40 shorts (80B): <=2-way bank alias (free)
  __shared__ ushort Bs[128][40];
  int tid = threadIdx.x;
  int r = tid >> 1, h = (tid & 1) << 4;     // h in shorts: 0 / 16
  int lane = tid & 63, w = tid >> 6;
  int wr = w >> 1, wc = w & 1;              // 2x2 wave grid, 64x64 per wave
  int sidx = base + row0 + r; if (sidx > SLOTS-1) sidx = SLOTS-1;
  const ushort* Ap = A + (size_t)sidx * kld + h;
  const ushort* Bp = Bt + (size_t)e * ((size_t)FFD*DM) + (size_t)(col0 + r) * ldb + h;
  uint4 pa0 = *(const uint4*)Ap;
  uint4 pa1 = *(const uint4*)(Ap + 8);
  uint4 pb0 = *(const uint4*)Bp;
  uint4 pb1 = *(const uint4*)(Bp + 8);
  f32x4 acc[4][4] = {};
  int fr = lane & 15, ksel = (lane >> 4) << 3;
  int k0 = 0;
  while (true){
    __syncthreads();
    *(uint4*)&As[r][h]     = pa0;
    *(uint4*)&As[r][h + 8] = pa1;
    *(uint4*)&Bs[r][h]     = pb0;
    *(uint4*)&Bs[r][h + 8] = pb1;
    __syncthreads();
    k0 += 32;
    if (k0 < kld){
      pa0 = *(const uint4*)(Ap + k0);
      pa1 = *(const uint4*)(Ap + k0 + 8);
      pb0 = *(const uint4*)(Bp + k0);
      pb1 = *(const uint4*)(Bp + k0 + 8);
    }
    bf16x8 af[4], bf[4];
    #pragma unroll
    for (int i = 0; i < 4; ++i){
      af[i] = *(const bf16x8*)&As[(wr<<6) + (i<<4) + fr][ksel];
      bf[i] = *(const bf16x8*)&Bs[(wc<<6) + (i<<4) + fr][ksel];
    }
    #pragma unroll
    for (int i = 0; i < 4; ++i)
      #pragma unroll
      for (int j = 0; j < 4; ++j)
        acc[i][j] = __builtin_amdgcn_mfma_f32_16x16x32_bf16(af[i], bf[j], acc[i][j], 0, 0, 0);
    if (k0 >= kld) break;
  }
  // C/D layout (m89-verified): row = (lane>>4)*4 + q, col = lane&15
  int fq = lane >> 4;
  #pragma unroll
  for (int j = 0; j < 4; ++j){
    int col = col0 + (wc<<6) + (j<<4) + fr;
    float bv = bias[(size_t)e * ((MODE==0)?FFD:DM) + col];
    #pragma unroll
    for (int i = 0; i < 4; ++i){
      #pragma unroll
      for (int q = 0; q < 4; ++q){
        int rr = row0 + (wr<<6) + (i<<4) + (fq<<2) + q;
        if (rr < cnt){
          if (MODE == 0){
            float vv = acc[i][j][q] + bv;
            ((ushort*)Out)[(size_t)(base+rr)*out_ld + col] = f2bf(fmaxf(vv, 0.f));
          } else {
            float* yp = (float*)Out + (size_t)(base+rr)*out_ld + col;
            *yp = acc[i][j][q] + (accum ? *yp : bv);
          }
        }
      }
    }
  }
}

// ---------------- gated combine + layernorm ----------------
__global__ __launch_bounds__(256)
void combine_ln_k(const float* __restrict__ Ye, const int* __restrict__ tok_slot,
                  const float* __restrict__ tok_g, const float* __restrict__ g,
                  const float* __restrict__ bb, float* __restrict__ F)
{
  int t = blockIdx.x, tid = threadIdx.x;
  int s1 = tok_slot[t*2], s2 = tok_slot[t*2+1];
  float g1 = tok_g[t*2], g2 = tok_g[t*2+1];
  const float* y1 = Ye + (size_t)s1*DM;
  const float* y2 = Ye + (size_t)s2*DM;
  float v0 = g1*y1[tid]     + g2*y2[tid];
  float v1 = g1*y1[tid+256] + g2*y2[tid+256];
  __shared__ float red[8];
  int w = tid >> 6, lane = tid & 63;
  float s = v0 + v1;
  #pragma unroll
  for (int off = 32; off; off >>= 1) s += __shfl_xor(s, off, 64);
  if (lane == 0) red[w] = s;
  __syncthreads();
  float mu = (red[0]+red[1]+red[2]+red[3]) * (1.f/512.f);
  float d0 = v0 - mu, d1 = v1 - mu;
  float q2 = d0*d0 + d1*d1;
  #pragma unroll
  for (int off = 32; off; off >>= 1) q2 += __shfl_xor(q2, off, 64);
  if (lane == 0) red[4+w] = q2;
  __syncthreads();
  float var = (red[4]+red[5]+red[6]+red[7]) * (1.f/512.f);
  float r = 1.f / sqrtf(var + 1e-5f);
  F[(size_t)t*DM + tid]       = d0*r*g[tid]     + bb[tid];
  F[(size_t)t*DM + tid + 256] = d1*r*g[tid+256] + bb[tid+256];
}

// ---------------- global = sum over T of second_vector ----------------
__global__ void gsum_k(const float* __restrict__ sv, float* __restrict__ gb, float* __restrict__ gout){
  int i = blockIdx.x*256 + threadIdx.x;
  int b = i >> 9, d = i & 511;
  const float* p = sv + (size_t)b*TT*DM + d;
  float s = 0.f;
  for (int t = 0; t < TT; ++t) s += p[(size_t)t*DM];
  gb[i] = s; gout[i] = s;
}

extern "C" void kernel_launch(void* const* d_in, const int* in_sizes, int n_in,
                              void* d_out, int out_size, void* d_ws, size_t ws_size,
                              hipStream_t stream)
{
  (void)in_sizes; (void)n_in; (void)out_size;
  const float* xin   = (const float*)d_in[0];
  const float* pembW = (const float*)d_in[1];
  const float* pembB = (const float*)d_in[2];
  const float* vecW  = (const float*)d_in[3];
  const float* vecB  = (const float*)d_in[4];
  const float* clsW  = (const float*)d_in[5];
  const float* clsB  = (const float*)d_in[6];
  float* out = (float*)d_out;

  // ---- choose MoE chunk width by available workspace ----
  const size_t SMALLF = 16384*2 + 12544*5 + 64;
  const size_t WTF = (size_t)NE * FFD * DM / 2;       // floats for one bf16 weight copy
  const size_t XGF = (size_t)SLOTS * DM / 2;          // floats for bf16 Xg
  int fcw = 256;
  for (int cand = 2048; cand >= 256; cand >>= 1){
    size_t need = ((size_t)4*ABUF + (size_t)SLOTS*cand/2 + XGF + 2*WTF + SMALLF) * sizeof(float);
    if (need <= ws_size){ fcw = cand; break; }
  }

  float* ws = (float*)d_ws;
  float* A0   = ws;
  float* A1   = A0 + ABUF;
  float* A2   = A1 + ABUF;           // Yexp spans A2..A3 (12544*512 f32)
  float* A3   = A2 + ABUF;
  float* H1f  = A3 + ABUF;           // bf16 H1: SLOTS*fcw shorts
  ushort* H1b = (ushort*)H1f;
  float* Xgf  = H1f + (size_t)SLOTS * fcw / 2;
  ushort* Xg  = (ushort*)Xgf;
  float* WiTf = Xgf + XGF;
  ushort* WiT = (ushort*)WiTf;
  float* WoTf = WiTf + WTF;
  ushort* WoT = (ushort*)WoTf;
  float* Yexp = A2;
  float* patches = H1f;              // alias: dead before MoE (needs 1,605,632 f <= SLOTS*256/2)
  float* pe      = Xgf;              // alias: dead before MoE (needs 100,352 f)
  float* gbv    = WoTf + WTF;
  float* clsbuf = gbv + 16384;
  float* tok_g  = clsbuf + 16384;
  int*   tok_e  = (int*)(tok_g + 12544);
  int*   tok_slot = tok_e + 12544;
  int*   idx_c  = tok_slot + 12544;
  int*   offs   = idx_c + 12544;     // 9 ints

  patchify_k<<<dim3(BT), dim3(256), 0, stream>>>(xin, patches);
  posenc_k<<<dim3(TT), dim3(512), 0, stream>>>(pe);
  gemm128<<<dim3(4,49), dim3(256), 0, stream>>>(patches, pembW, A1, pembB, pe, nullptr, DM, 256);

  float* P = A1;
  float* Q = A0;
  for (int l = 0; l < 2; ++l){
    int base = 7 + 18*l;
    const float* pW  = (const float*)d_in[base+0];
    const float* pb  = (const float*)d_in[base+1];
    const float* Wq  = (const float*)d_in[base+2];
    const float* Wk  = (const float*)d_in[base+3];
    const float* Wv  = (const float*)d_in[base+4];
    const float* Wo  = (const float*)d_in[base+5];
    const float* bo  = (const float*)d_in[base+6];
    const float* rtW = (const float*)d_in[base+7];
    const float* rtb = (const float*)d_in[base+8];
    const float* rnW = (const float*)d_in[base+9];
    const float* rnb = (const float*)d_in[base+10];
    const float* eWi = (const float*)d_in[base+11];
    const float* ebi = (const float*)d_in[base+12];
    const float* eWo = (const float*)d_in[base+13];
    const float* ebo = (const float*)d_in[base+14];
    const float* lng = (const float*)d_in[base+15];
    const float* lnb = (const float*)d_in[base+16];
    const float* nz  = (const float*)d_in[base+17];

    gemm128<<<dim3(4,49), dim3(256), 0, stream>>>(P, pW, Q, pb, nullptr, nullptr, DM, DM);
    gemm128<<<dim3(4,49), dim3(256), 0, stream>>>(Q, Wq, P, nullptr, nullptr, nullptr, DM, DM);
    gemm128<<<dim3(4,49), dim3(256), 0, stream>>>(Q, Wk, A2, nullptr, nullptr, nullptr, DM, DM);
    gemm128<<<dim3(4,49), dim3(256), 0, stream>>>(Q, Wv, A3, nullptr, nullptr, nullptr, DM, DM);
    fattn_k<<<dim3(4,256), dim3(256), 0, stream>>>(P, A2, A3, P);
    gemm128<<<dim3(4,49), dim3(256), 0, stream>>>(P, Wo, Q, bo, nullptr, nullptr, DM, DM);
    // expert weights -> bf16, N-major (k-contiguous) layout
    transconv_k<<<dim3(FFD/32, DM/32, NE), dim3(256), 0, stream>>>(eWi, WiT, DM, FFD);
    transconv_k<<<dim3(DM/32, FFD/32, NE), dim3(256), 0, stream>>>(eWo, WoT, FFD, DM);
    // routing
    router2_k<<<dim3(BT/4), dim3(256), 0, stream>>>(Q, rtW, rtb, rnW, rnb, nz, tok_e, tok_g);
    route_assign_k<<<dim3(1), dim3(1024), 0, stream>>>(tok_e, offs, idx_c, tok_slot);
    gatherconv_k<<<dim3(SLOTS), dim3(256), 0, stream>>>(Q, idx_c, Xg);
    // experts (MFMA; chunked only if workspace forces it)
    for (int c0 = 0; c0 < FFD; c0 += fcw){
      moe_mfma<0><<<dim3(fcw/128, 49, NE), dim3(256), 0, stream>>>(
          Xg, WiT + (size_t)c0*DM, ebi + c0, offs, (void*)H1b, DM, DM, fcw, 0);
      moe_mfma<1><<<dim3(DM/128, 49, NE), dim3(256), 0, stream>>>(
          H1b, WoT + c0, ebo, offs, (void*)Yexp, fcw, FFD, DM, c0);
    }
    combine_ln_k<<<dim3(BT), dim3(256), 0, stream>>>(Yexp, tok_slot, tok_g, lng, lnb, P);
    float* mirror = out + (size_t)l * ABUF;
    gemm128<<<dim3(4,49), dim3(256), 0, stream>>>(P, vecW, Q, vecB, nullptr, mirror, DM, DM);
    float* tmp = P; P = Q; Q = tmp;
  }

  gsum_k<<<dim3(64), dim3(256), 0, stream>>>(P, gbv, out + 2*ABUF);
  gemm_f32<<<dim3(8,1), dim3(256), 0, stream>>>(gbv, clsW, clsbuf, clsB, out + 2*ABUF + 16384, 32, DM, DM);
}

// Round 2
// 1228.812 us; speedup vs baseline: 2.3772x; 1.3236x over previous
//
#include <hip/hip_runtime.h>

#define BT 6272      // B*T = 32*196
#define TT 196
#define DM 512
#define FFD 2048
#define NE 8
#define ABUF 3211264 // activation buffer elems (6272*512)
#define SLOTS 12544  // BT*2 expert slots

typedef float f32x4 __attribute__((ext_vector_type(4)));
typedef __bf16 bf16x8 __attribute__((ext_vector_type(8)));

__device__ __forceinline__ ushort f2bf(float f){
  union { float f; unsigned u; } v; v.f = f;
  unsigned u = v.u;
  u += 0x7fffu + ((u >> 16) & 1u);   // RNE
  return (ushort)(u >> 16);
}

// split fp32 into bf16 hi (truncated) + bf16 lo (RNE of remainder): a ~= hi + lo, err ~2^-17
__device__ __forceinline__ void splitbf(float v, ushort& hi, ushort& lo){
  union { float f; unsigned u; } c; c.f = v;
  hi = (ushort)(c.u >> 16);
  union { unsigned u; float f; } hf; hf.u = c.u & 0xffff0000u;
  lo = f2bf(v - hf.f);
}

// ---------------- patchify: x[B,1,224,224] f32 -> split-bf16 patches[BT,256] ----------------
__global__ void patchify_k(const float* __restrict__ x, ushort* __restrict__ oh, ushort* __restrict__ ol){
  int bt = blockIdx.x;
  int t = bt % TT, b = bt / TT;
  int pd = threadIdx.x;
  int g1 = t / 14, g2 = t % 14, p1 = pd >> 4, p2 = pd & 15;
  int src = (b*224 + g1*16 + p1)*224 + g2*16 + p2;
  float v = x[src];
  ushort hu, lu; splitbf(v, hu, lu);
  oh[(size_t)bt*256 + pd] = hu;
  ol[(size_t)bt*256 + pd] = lu;
}

// ---------------- posenc[196,512] f32 ----------------
__global__ void posenc_k(float* __restrict__ pe){
  int t = blockIdx.x, c = threadIdx.x;
  int m2 = c & ~1;
  double ang = (double)t * pow(10000.0, -(double)m2 / 512.0);
  double vv = (c & 1) ? cos(ang) : sin(ang);
  pe[t*DM + c] = (float)vv;
}

// ---------------- weight transpose + split: src[R][C] f32 -> dh/dl[C][R] bf16 hi/lo ----------------
__global__ __launch_bounds__(256)
void wsplit_k(const float* __restrict__ src, ushort* __restrict__ dh, ushort* __restrict__ dl,
              int R, int C){
  __shared__ float t[32][33];
  int c0 = blockIdx.x << 5, r0 = blockIdx.y << 5;
  int tx = threadIdx.x & 31, ty = threadIdx.x >> 5;
  #pragma unroll
  for (int i = 0; i < 32; i += 8)
    t[ty+i][tx] = src[(size_t)(r0+ty+i)*C + c0 + tx];
  __syncthreads();
  #pragma unroll
  for (int i = 0; i < 32; i += 8){
    float v = t[tx][ty+i];
    ushort hu, lu; splitbf(v, hu, lu);
    dh[(size_t)(c0+ty+i)*R + r0 + tx] = hu;
    dl[(size_t)(c0+ty+i)*R + r0 + tx] = lu;
  }
}

// ---------------- dense split-bf16 MFMA GEMM: [6272 x 512] = A[6272,kld] @ B^T, 128x128 tile ----------------
// A: split pair [M][kld] k-contig; B: split pair [512][kld] k-contig (pre-transposed weights).
// Outputs any of: Cf fp32, (Ch,Cl) split-bf16. Optional bias[col], optional posenc add.
__global__ __launch_bounds__(256)
void gemm_s(const ushort* __restrict__ Ah, const ushort* __restrict__ Al,
            const ushort* __restrict__ Bh, const ushort* __restrict__ Bl,
            const float* __restrict__ bias, const float* __restrict__ pe,
            float* __restrict__ Cf, ushort* __restrict__ Ch, ushort* __restrict__ Cl,
            int kld)
{
  __shared__ ushort Ahs[128][40];   // +8 pad: <=2-way bank alias (free)
  __shared__ ushort Als[128][40];
  __shared__ ushort Bhs[128][40];
  __shared__ ushort Bls[128][40];
  int tid = threadIdx.x;
  int row0 = blockIdx.y << 7, col0 = blockIdx.x << 7;
  int r = tid >> 1, h = (tid & 1) << 4;
  int lane = tid & 63, w = tid >> 6;
  int wr = w >> 1, wc = w & 1;
  const ushort* Aph = Ah + (size_t)(row0 + r) * kld + h;
  const ushort* Apl = Al + (size_t)(row0 + r) * kld + h;
  const ushort* Bph = Bh + (size_t)(col0 + r) * kld + h;
  const ushort* Bpl = Bl + (size_t)(col0 + r) * kld + h;
  f32x4 acc[4][4] = {};
  int fr = lane & 15, ksel = (lane >> 4) << 3;
  for (int k0 = 0; k0 < kld; k0 += 32){
    __syncthreads();
    *(uint4*)&Ahs[r][h]   = *(const uint4*)(Aph + k0);
    *(uint4*)&Ahs[r][h+8] = *(const uint4*)(Aph + k0 + 8);
    *(uint4*)&Als[r][h]   = *(const uint4*)(Apl + k0);
    *(uint4*)&Als[r][h+8] = *(const uint4*)(Apl + k0 + 8);
    *(uint4*)&Bhs[r][h]   = *(const uint4*)(Bph + k0);
    *(uint4*)&Bhs[r][h+8] = *(const uint4*)(Bph + k0 + 8);
    *(uint4*)&Bls[r][h]   = *(const uint4*)(Bpl + k0);
    *(uint4*)&Bls[r][h+8] = *(const uint4*)(Bpl + k0 + 8);
    __syncthreads();
    bf16x8 ah[4], al[4];
    #pragma unroll
    for (int i = 0; i < 4; ++i){
      ah[i] = *(const bf16x8*)&Ahs[(wr<<6) + (i<<4) + fr][ksel];
      al[i] = *(const bf16x8*)&Als[(wr<<6) + (i<<4) + fr][ksel];
    }
    #pragma unroll
    for (int j = 0; j < 4; ++j){
      bf16x8 bh = *(const bf16x8*)&Bhs[(wc<<6) + (j<<4) + fr][ksel];
      bf16x8 bl = *(const bf16x8*)&Bls[(wc<<6) + (j<<4) + fr][ksel];
      #pragma unroll
      for (int i = 0; i < 4; ++i){
        acc[i][j] = __builtin_amdgcn_mfma_f32_16x16x32_bf16(ah[i], bh, acc[i][j], 0, 0, 0);
        acc[i][j] = __builtin_amdgcn_mfma_f32_16x16x32_bf16(al[i], bh, acc[i][j], 0, 0, 0);
        acc[i][j] = __builtin_amdgcn_mfma_f32_16x16x32_bf16(ah[i], bl, acc[i][j], 0, 0, 0);
      }
    }
  }
  int fq = lane >> 4;
  #pragma unroll
  for (int j = 0; j < 4; ++j){
    int col = col0 + (wc<<6) + (j<<4) + fr;
    float bv = bias ? bias[col] : 0.f;
    #pragma unroll
    for (int i = 0; i < 4; ++i){
      #pragma unroll
      for (int q = 0; q < 4; ++q){
        int rr = row0 + (wr<<6) + (i<<4) + (fq<<2) + q;
        float v = acc[i][j][q] + bv;
        if (pe) v += pe[(size_t)(rr % TT)*DM + col];
        size_t off = (size_t)rr*DM + col;
        if (Cf) Cf[off] = v;
        if (Ch){
          ushort hu, lu; splitbf(v, hu, lu);
          Ch[off] = hu; Cl[off] = lu;
        }
      }
    }
  }
}

// ---------------- old 64x64 GEMM (kept for the tiny cls matmul, M=32) ----------------
__global__ __launch_bounds__(256)
void gemm_f32(const float* __restrict__ A, const float* __restrict__ Bw,
              float* __restrict__ C, const float* __restrict__ bias,
              float* __restrict__ obf, int M, int N, int K)
{
  __shared__ float As[16][68];
  __shared__ float Bs[16][68];
  int tid = threadIdx.x;
  int row0 = blockIdx.y << 6, col0 = blockIdx.x << 6;
  int ar = tid >> 2, ak = (tid & 3) << 2;
  int bk = tid >> 4, bn = (tid & 15) << 2;
  int n0 = (tid & 15) << 2, m0 = (tid >> 4) << 2;
  float acc[4][4] = {};
  bool arow_ok = (row0 + ar) < M;
  const float* Aldg = A + (size_t)(row0 + ar) * K + ak;
  const float* Bldg = Bw + (size_t)bk * N + col0 + bn;
  for (int k0 = 0; k0 < K; k0 += 16){
    float4 av = make_float4(0.f,0.f,0.f,0.f);
    if (arow_ok) av = *(const float4*)(Aldg + k0);
    float4 bv = *(const float4*)(Bldg + (size_t)k0 * N);
    __syncthreads();
    As[ak+0][ar]=av.x; As[ak+1][ar]=av.y; As[ak+2][ar]=av.z; As[ak+3][ar]=av.w;
    *(float4*)&Bs[bk][bn] = bv;
    __syncthreads();
    #pragma unroll
    for (int kk = 0; kk < 16; ++kk){
      float4 a = *(const float4*)&As[kk][m0];
      float4 b = *(const float4*)&Bs[kk][n0];
      float aa[4] = {a.x,a.y,a.z,a.w};
      float bb[4] = {b.x,b.y,b.z,b.w};
      #pragma unroll
      for (int i = 0; i < 4; ++i)
        #pragma unroll
        for (int j = 0; j < 4; ++j)
          acc[i][j] += aa[i]*bb[j];
    }
  }
  float4 badd = make_float4(0.f,0.f,0.f,0.f);
  if (bias) badd = *(const float4*)(bias + col0 + n0);
  #pragma unroll
  for (int i = 0; i < 4; ++i){
    int gr = row0 + m0 + i;
    if (gr < M){
      float4 r = make_float4(acc[i][0]+badd.x, acc[i][1]+badd.y, acc[i][2]+badd.z, acc[i][3]+badd.w);
      *(float4*)(C + (size_t)gr*N + col0 + n0) = r;
      if (obf) *(float4*)(obf + (size_t)gr*N + col0 + n0) = r;
    }
  }
}

// ---------------- flash-style causal attention; output written as split-bf16 ----------------
__global__ __launch_bounds__(256)
void fattn_k(const float* __restrict__ q, const float* __restrict__ k,
             const float* __restrict__ v, ushort* __restrict__ oh, ushort* __restrict__ ol)
{
  __shared__ float Qt[64][68];
  __shared__ float KP[64][68];
  __shared__ float Vs[64][68];
  int qt = blockIdx.x, bh = blockIdx.y;
  int b = bh >> 3, h = bh & 7;
  size_t base = (size_t)b * TT * DM + h * 64;
  int tid = threadIdx.x;
  int ty = tid >> 4, tx = tid & 15;
  int m0 = ty << 2, n0 = tx << 2;
  {
    int r = tid >> 2, dd = (tid & 3) << 4;
    int qrow = qt*64 + r;
    const float* qp = q + base + (size_t)(qrow < TT ? qrow : TT-1) * DM;
    #pragma unroll
    for (int u = 0; u < 4; ++u){
      float4 t4 = *(const float4*)(qp + dd + u*4);
      Qt[dd+u*4+0][r]=t4.x; Qt[dd+u*4+1][r]=t4.y; Qt[dd+u*4+2][r]=t4.z; Qt[dd+u*4+3][r]=t4.w;
    }
  }
  float o_acc[4][4] = {};
  float m_i[4], l_i[4];
  #pragma unroll
  for (int i = 0; i < 4; ++i){ m_i[i] = -3e38f; l_i[i] = 0.f; }
  int ktiles = qt + 1;
  for (int kt = 0; kt < ktiles; ++kt){
    __syncthreads();
    {
      int r = tid >> 2, dd = (tid & 3) << 4;
      int jrow = kt*64 + r;
      int jc = jrow < TT ? jrow : TT-1;
      const float* kp = k + base + (size_t)jc * DM;
      const float* vp = v + base + (size_t)jc * DM;
      #pragma unroll
      for (int u = 0; u < 4; ++u){
        float4 t4 = *(const float4*)(kp + dd + u*4);
        KP[dd+u*4+0][r]=t4.x; KP[dd+u*4+1][r]=t4.y; KP[dd+u*4+2][r]=t4.z; KP[dd+u*4+3][r]=t4.w;
        *(float4*)&Vs[r][dd + u*4] = *(const float4*)(vp + dd + u*4);
      }
    }
    __syncthreads();
    float s[4][4] = {};
    #pragma unroll 8
    for (int d = 0; d < 64; ++d){
      float4 a = *(const float4*)&Qt[d][m0];
      float4 bb = *(const float4*)&KP[d][n0];
      float xa[4] = {a.x,a.y,a.z,a.w};
      float yb[4] = {bb.x,bb.y,bb.z,bb.w};
      #pragma unroll
      for (int i = 0; i < 4; ++i)
        #pragma unroll
        for (int j = 0; j < 4; ++j)
          s[i][j] += xa[i]*yb[j];
    }
    int qrow0 = qt*64 + m0, jcol0 = kt*64 + n0;
    #pragma unroll
    for (int i = 0; i < 4; ++i)
      #pragma unroll
      for (int j = 0; j < 4; ++j){
        int jj = jcol0 + j;
        s[i][j] = (jj <= qrow0 + i && jj < TT) ? s[i][j]*0.125f : -3e38f;
      }
    float p[4][4];
    #pragma unroll
    for (int i = 0; i < 4; ++i){
      float mx = fmaxf(fmaxf(s[i][0],s[i][1]), fmaxf(s[i][2],s[i][3]));
      #pragma unroll
      for (int off = 1; off < 16; off <<= 1) mx = fmaxf(mx, __shfl_xor(mx, off, 64));
      float mnew = fmaxf(m_i[i], mx);
      float al = expf(m_i[i] - mnew);
      l_i[i] *= al;
      #pragma unroll
      for (int c = 0; c < 4; ++c) o_acc[i][c] *= al;
      float ps = 0.f;
      #pragma unroll
      for (int j = 0; j < 4; ++j){ p[i][j] = expf(s[i][j] - mnew); ps += p[i][j]; }
      #pragma unroll
      for (int off = 1; off < 16; off <<= 1) ps += __shfl_xor(ps, off, 64);
      l_i[i] += ps;
      m_i[i] = mnew;
    }
    __syncthreads();
    #pragma unroll
    for (int i = 0; i < 4; ++i)
      #pragma unroll
      for (int j = 0; j < 4; ++j)
        KP[n0 + j][m0 + i] = p[i][j];
    __syncthreads();
    #pragma unroll 8
    for (int jj = 0; jj < 64; ++jj){
      float4 a = *(const float4*)&KP[jj][m0];
      float4 bb = *(const float4*)&Vs[jj][n0];
      float xa[4] = {a.x,a.y,a.z,a.w};
      float yb[4] = {bb.x,bb.y,bb.z,bb.w};
      #pragma unroll
      for (int i = 0; i < 4; ++i)
        #pragma unroll
        for (int c = 0; c < 4; ++c)
          o_acc[i][c] += xa[i]*yb[c];
    }
  }
  #pragma unroll
  for (int i = 0; i < 4; ++i){
    int qrow = qt*64 + m0 + i;
    if (qrow < TT){
      float inv = 1.f / l_i[i];
      size_t idx = base + (size_t)qrow*DM + n0;
      ushort4 hv, lv;
      float v0 = o_acc[i][0]*inv, v1 = o_acc[i][1]*inv, v2 = o_acc[i][2]*inv, v3 = o_acc[i][3]*inv;
      splitbf(v0, hv.x, lv.x); splitbf(v1, hv.y, lv.y);
      splitbf(v2, hv.z, lv.z); splitbf(v3, hv.w, lv.w);
      *(ushort4*)(oh + idx) = hv;
      *(ushort4*)(ol + idx) = lv;
    }
  }
}

// ---------------- router: LDS-staged transposed weights, no atomics ----------------
__global__ __launch_bounds__(256)
void router2_k(const float* __restrict__ X, const float* __restrict__ rtW, const float* __restrict__ rtb,
               const float* __restrict__ rnW, const float* __restrict__ rnb, const float* __restrict__ nz,
               int* __restrict__ tok_e, float* __restrict__ tok_g)
{
  __shared__ float Wt[8*513];
  __shared__ float Wn[8*513];
  int tid = threadIdx.x;
  for (int i = tid*4; i < DM*8; i += 1024){
    float4 t = *(const float4*)(rtW + i);
    float4 n = *(const float4*)(rnW + i);
    int d = i >> 3, e = i & 7;
    Wt[(e+0)*513 + d] = t.x; Wt[(e+1)*513 + d] = t.y; Wt[(e+2)*513 + d] = t.z; Wt[(e+3)*513 + d] = t.w;
    Wn[(e+0)*513 + d] = n.x; Wn[(e+1)*513 + d] = n.y; Wn[(e+2)*513 + d] = n.z; Wn[(e+3)*513 + d] = n.w;
  }
  __syncthreads();
  int w = tid >> 6, lane = tid & 63;
  int t = (blockIdx.x << 2) + w;
  const float* xr = X + (size_t)t * DM;
  float at[8] = {}, an[8] = {};
  #pragma unroll
  for (int u = 0; u < 8; ++u){
    int d = (u<<6) + lane;
    float xv = xr[d];
    #pragma unroll
    for (int e = 0; e < 8; ++e){
      at[e] += xv * Wt[e*513 + d];
      an[e] += xv * Wn[e*513 + d];
    }
  }
  #pragma unroll
  for (int off = 32; off; off >>= 1){
    #pragma unroll
    for (int e = 0; e < 8; ++e){
      at[e] += __shfl_xor(at[e], off, 64);
      an[e] += __shfl_xor(an[e], off, 64);
    }
  }
  if (lane == 0){
    float ns[8];
    #pragma unroll
    for (int e = 0; e < 8; ++e){
      float lt = at[e] + rtb[e];
      float ln_ = an[e] + rnb[e];
      float sp = (ln_ > 0.f) ? (ln_ + log1pf(expf(-ln_))) : log1pf(expf(ln_));
      ns[e] = lt + nz[(size_t)t*8 + e] * sp;
    }
    int i1 = 0; float n1 = ns[0];
    #pragma unroll
    for (int e = 1; e < 8; ++e) if (ns[e] > n1){ n1 = ns[e]; i1 = e; }
    int i2 = -1; float n2 = -3e38f;
    #pragma unroll
    for (int e = 0; e < 8; ++e) if (e != i1 && ns[e] > n2){ n2 = ns[e]; i2 = e; }
    float ex = expf(n2 - n1);
    float inv = 1.f / (1.f + ex);
    tok_e[t*2]   = i1; tok_g[t*2]   = inv;
    tok_e[t*2+1] = i2; tok_g[t*2+1] = ex * inv;
  }
}

// ---------------- single-block histogram + prefix + slot assignment ----------------
__global__ __launch_bounds__(1024)
void route_assign_k(const int* __restrict__ tok_e, int* __restrict__ offs_g,
                    int* __restrict__ idx_c, int* __restrict__ tok_slot)
{
  __shared__ int hist[NE];
  __shared__ int cur[NE];
  int tid = threadIdx.x;
  if (tid < NE) hist[tid] = 0;
  __syncthreads();
  for (int i = tid; i < BT*2; i += 1024) atomicAdd(&hist[tok_e[i]], 1);
  __syncthreads();
  if (tid == 0){
    int s = 0;
    for (int e = 0; e < NE; ++e){ offs_g[e] = s; cur[e] = s; s += hist[e]; }
    offs_g[NE] = s;
  }
  __syncthreads();
  for (int i = tid; i < BT*2; i += 1024){
    int e = tok_e[i];
    int p = atomicAdd(&cur[e], 1);
    idx_c[p] = i >> 1;
    tok_slot[i] = p;
  }
}

// ---------------- transpose + f32->bf16 convert (expert weights): src[R][C] -> dst[C][R] ----------------
__global__ __launch_bounds__(256)
void transconv_k(const float* __restrict__ src, ushort* __restrict__ dst, int R, int C){
  __shared__ float t[32][33];
  int e = blockIdx.z;
  src += (size_t)e * R * C;
  dst += (size_t)e * R * C;
  int c0 = blockIdx.x << 5, r0 = blockIdx.y << 5;
  int tx = threadIdx.x & 31, ty = threadIdx.x >> 5;
  #pragma unroll
  for (int i = 0; i < 32; i += 8)
    t[ty+i][tx] = src[(size_t)(r0+ty+i)*C + c0 + tx];
  __syncthreads();
  #pragma unroll
  for (int i = 0; i < 32; i += 8)
    dst[(size_t)(c0+ty+i)*R + r0 + tx] = f2bf(t[tx][ty+i]);
}

// ---------------- gather routed rows + convert to bf16: Xg[slot][512] ----------------
__global__ void gatherconv_k(const float* __restrict__ X, const int* __restrict__ idx,
                             ushort* __restrict__ Xg){
  int s = blockIdx.x;
  const float* xp = X + (size_t)idx[s] * DM;
  ushort* op = Xg + (size_t)s * DM;
  int i = threadIdx.x * 2;
  float2 v = *(const float2*)(xp + i);
  ushort2 o; o.x = f2bf(v.x); o.y = f2bf(v.y);
  *(ushort2*)(op + i) = o;
}

// ---------------- MoE expert GEMM, bf16 MFMA 16x16x32, 128x128 tile, 4 waves ----------------
template<int MODE>
__global__ __launch_bounds__(256)
void moe_mfma(const ushort* __restrict__ A, const ushort* __restrict__ Bt,
              const float* __restrict__ bias, const int* __restrict__ offs,
              void* __restrict__ Out, int kld, int ldb, int out_ld, int accum)
{
  int e = blockIdx.z;
  int base = offs[e], cnt = offs[e+1] - base;
  int row0 = blockIdx.y << 7;
  if (row0 >= cnt) return;
  int col0 = blockIdx.x << 7;
  __shared__ ushort As[128][40];
  __shared__ ushort Bs[128][40];
  int tid = threadIdx.x;
  int r = tid >> 1, h = (tid & 1) << 4;
  int lane = tid & 63, w = tid >> 6;
  int wr = w >> 1, wc = w & 1;
  int sidx = base + row0 + r; if (sidx > SLOTS-1) sidx = SLOTS-1;
  const ushort* Ap = A + (size_t)sidx * kld + h;
  const ushort* Bp = Bt + (size_t)e * ((size_t)FFD*DM) + (size_t)(col0 + r) * ldb + h;
  uint4 pa0 = *(const uint4*)Ap;
  uint4 pa1 = *(const uint4*)(Ap + 8);
  uint4 pb0 = *(const uint4*)Bp;
  uint4 pb1 = *(const uint4*)(Bp + 8);
  f32x4 acc[4][4] = {};
  int fr = lane & 15, ksel = (lane >> 4) << 3;
  int k0 = 0;
  while (true){
    __syncthreads();
    *(uint4*)&As[r][h]     = pa0;
    *(uint4*)&As[r][h + 8] = pa1;
    *(uint4*)&Bs[r][h]     = pb0;
    *(uint4*)&Bs[r][h + 8] = pb1;
    __syncthreads();
    k0 += 32;
    if (k0 < kld){
      pa0 = *(const uint4*)(Ap + k0);
      pa1 = *(const uint4*)(Ap + k0 + 8);
      pb0 = *(const uint4*)(Bp + k0);
      pb1 = *(const uint4*)(Bp + k0 + 8);
    }
    bf16x8 af[4], bf[4];
    #pragma unroll
    for (int i = 0; i < 4; ++i){
      af[i] = *(const bf16x8*)&As[(wr<<6) + (i<<4) + fr][ksel];
      bf[i] = *(const bf16x8*)&Bs[(wc<<6) + (i<<4) + fr][ksel];
    }
    #pragma unroll
    for (int i = 0; i < 4; ++i)
      #pragma unroll
      for (int j = 0; j < 4; ++j)
        acc[i][j] = __builtin_amdgcn_mfma_f32_16x16x32_bf16(af[i], bf[j], acc[i][j], 0, 0, 0);
    if (k0 >= kld) break;
  }
  int fq = lane >> 4;
  #pragma unroll
  for (int j = 0; j < 4; ++j){
    int col = col0 + (wc<<6) + (j<<4) + fr;
    float bv = bias[(size_t)e * ((MODE==0)?FFD:DM) + col];
    #pragma unroll
    for (int i = 0; i < 4; ++i){
      #pragma unroll
      for (int q = 0; q < 4; ++q){
        int rr = row0 + (wr<<6) + (i<<4) + (fq<<2) + q;
        if (rr < cnt){
          if (MODE == 0){
            float vv = acc[i][j][q] + bv;
            ((ushort*)Out)[(size_t)(base+rr)*out_ld + col] = f2bf(fmaxf(vv, 0.f));
          } else {
            float* yp = (float*)Out + (size_t)(base+rr)*out_ld + col;
            *yp = acc[i][j][q] + (accum ? *yp : bv);
          }
        }
      }
    }
  }
}

// ---------------- gated combine + layernorm; output as split-bf16 ----------------
__global__ __launch_bounds__(256)
void combine_ln_k(const float* __restrict__ Ye, const int* __restrict__ tok_slot,
                  const float* __restrict__ tok_g, const float* __restrict__ g,
                  const float* __restrict__ bb, ushort* __restrict__ oh, ushort* __restrict__ ol)
{
  int t = blockIdx.x, tid = threadIdx.x;
  int s1 = tok_slot[t*2], s2 = tok_slot[t*2+1];
  float g1 = tok_g[t*2], g2 = tok_g[t*2+1];
  const float* y1 = Ye + (size_t)s1*DM;
  const float* y2 = Ye + (size_t)s2*DM;
  float v0 = g1*y1[tid]     + g2*y2[tid];
  float v1 = g1*y1[tid+256] + g2*y2[tid+256];
  __shared__ float red[8];
  int w = tid >> 6, lane = tid & 63;
  float s = v0 + v1;
  #pragma unroll
  for (int off = 32; off; off >>= 1) s += __shfl_xor(s, off, 64);
  if (lane == 0) red[w] = s;
  __syncthreads();
  float mu = (red[0]+red[1]+red[2]+red[3]) * (1.f/512.f);
  float d0 = v0 - mu, d1 = v1 - mu;
  float q2 = d0*d0 + d1*d1;
  #pragma unroll
  for (int off = 32; off; off >>= 1) q2 += __shfl_xor(q2, off, 64);
  if (lane == 0) red[4+w] = q2;
  __syncthreads();
  float var = (red[4]+red[5]+red[6]+red[7]) * (1.f/512.f);
  float r = 1.f / sqrtf(var + 1e-5f);
  float r0v = d0*r*g[tid]     + bb[tid];
  float r1v = d1*r*g[tid+256] + bb[tid+256];
  ushort hu, lu;
  splitbf(r0v, hu, lu);
  oh[(size_t)t*DM + tid] = hu; ol[(size_t)t*DM + tid] = lu;
  splitbf(r1v, hu, lu);
  oh[(size_t)t*DM + tid + 256] = hu; ol[(size_t)t*DM + tid + 256] = lu;
}

// ---------------- global = sum over T of second_vector ----------------
__global__ void gsum_k(const float* __restrict__ sv, float* __restrict__ gb, float* __restrict__ gout){
  int i = blockIdx.x*256 + threadIdx.x;
  int b = i >> 9, d = i & 511;
  const float* p = sv + (size_t)b*TT*DM + d;
  float s = 0.f;
  for (int t = 0; t < TT; ++t) s += p[(size_t)t*DM];
  gb[i] = s; gout[i] = s;
}

extern "C" void kernel_launch(void* const* d_in, const int* in_sizes, int n_in,
                              void* d_out, int out_size, void* d_ws, size_t ws_size,
                              hipStream_t stream)
{
  (void)in_sizes; (void)n_in; (void)out_size;
  const float* xin   = (const float*)d_in[0];
  const float* pembW = (const float*)d_in[1];
  const float* pembB = (const float*)d_in[2];
  const float* vecW  = (const float*)d_in[3];
  const float* vecB  = (const float*)d_in[4];
  const float* clsW  = (const float*)d_in[5];
  const float* clsB  = (const float*)d_in[6];
  float* out = (float*)d_out;

  // ---- workspace budget: fixed part + H1(fcw) ----
  const size_t FIXEDF = (size_t)3*ABUF               // A0..A2 fp32
                      + (size_t)2*ABUF               // S0/S1 split pairs (4*ABUF shorts)
                      + (size_t)SLOTS*DM/2           // Xg shorts
                      + (size_t)NE*FFD*DM            // WiT+WoT shorts
                      + 655360                       // pemb/vec/Wd split pairs (shorts->floats)
                      + (size_t)TT*DM                // posenc
                      + 16384*2 + (size_t)SLOTS*4 + 64;
  int fcw = 256;
  for (int cand = 2048; cand >= 256; cand >>= 1){
    size_t need = (FIXEDF + (size_t)SLOTS*cand/2) * sizeof(float);
    if (need <= ws_size){ fcw = cand; break; }
  }

  float* ws = (float*)d_ws;
  float* A0 = ws;
  float* A1 = A0 + ABUF;
  float* A2 = A1 + ABUF;
  ushort* S0h = (ushort*)(A2 + ABUF);
  ushort* S0l = S0h + ABUF;
  ushort* S1h = S0l + ABUF;
  ushort* S1l = S1h + ABUF;
  ushort* H1b = S1l + ABUF;                       // SLOTS*fcw shorts
  ushort* Xg  = H1b + (size_t)SLOTS * fcw;
  ushort* WiT = Xg + (size_t)SLOTS * DM;
  ushort* WoT = WiT + (size_t)NE * FFD * DM;
  ushort* PembH = WoT + (size_t)NE * FFD * DM;    // [512][256]
  ushort* PembL = PembH + 256*DM;
  ushort* VecH  = PembL + 256*DM;                 // [512][512]
  ushort* VecL  = VecH + DM*DM;
  ushort* WdH   = VecL + DM*DM;                   // scratch pair for per-layer dense weights
  ushort* WdL   = WdH + DM*DM;
  float* pe     = (float*)(WdL + DM*DM);
  float* gbv    = pe + TT*DM;
  float* clsbuf = gbv + 16384;
  float* tok_g  = clsbuf + 16384;
  int*   tok_e  = (int*)(tok_g + SLOTS);
  int*   tok_slot = tok_e + SLOTS;
  int*   idx_c  = tok_slot + SLOTS;
  int*   offs   = idx_c + SLOTS;                  // 9 ints
  float* Yexp   = A1;                             // spans A1..A2 (SLOTS*512 fp32)

  patchify_k<<<dim3(BT), dim3(256), 0, stream>>>(xin, S0h, S0l);
  posenc_k<<<dim3(TT), dim3(512), 0, stream>>>(pe);
  wsplit_k<<<dim3(16, 8), dim3(256), 0, stream>>>(pembW, PembH, PembL, 256, DM);
  wsplit_k<<<dim3(16, 16), dim3(256), 0, stream>>>(vecW, VecH, VecL, DM, DM);
  // h = patches @ pembW + b + posenc  -> split into S1
  gemm_s<<<dim3(4,49), dim3(256), 0, stream>>>(S0h, S0l, PembH, PembL, pembB, pe,
                                               nullptr, S1h, S1l, 256);

  for (int l = 0; l < 2; ++l){
    int base = 7 + 18*l;
    const float* pW  = (const float*)d_in[base+0];
    const float* pb  = (const float*)d_in[base+1];
    const float* Wq  = (const float*)d_in[base+2];
    const float* Wk  = (const float*)d_in[base+3];
    const float* Wv  = (const float*)d_in[base+4];
    const float* Wo  = (const float*)d_in[base+5];
    const float* bo  = (const float*)d_in[base+6];
    const float* rtW = (const float*)d_in[base+7];
    const float* rtb = (const float*)d_in[base+8];
    const float* rnW = (const float*)d_in[base+9];
    const float* rnb = (const float*)d_in[base+10];
    const float* eWi = (const float*)d_in[base+11];
    const float* ebi = (const float*)d_in[base+12];
    const float* eWo = (const float*)d_in[base+13];
    const float* ebo = (const float*)d_in[base+14];
    const float* lng = (const float*)d_in[base+15];
    const float* lnb = (const float*)d_in[base+16];
    const float* nz  = (const float*)d_in[base+17];

    // input projection: S1 -> S0 (split only)
    wsplit_k<<<dim3(16,16), dim3(256), 0, stream>>>(pW, WdH, WdL, DM, DM);
    gemm_s<<<dim3(4,49), dim3(256), 0, stream>>>(S1h, S1l, WdH, WdL, pb, nullptr,
                                                 nullptr, S0h, S0l, DM);
    // q,k,v fp32 from S0
    wsplit_k<<<dim3(16,16), dim3(256), 0, stream>>>(Wq, WdH, WdL, DM, DM);
    gemm_s<<<dim3(4,49), dim3(256), 0, stream>>>(S0h, S0l, WdH, WdL, nullptr, nullptr,
                                                 A0, nullptr, nullptr, DM);
    wsplit_k<<<dim3(16,16), dim3(256), 0, stream>>>(Wk, WdH, WdL, DM, DM);
    gemm_s<<<dim3(4,49), dim3(256), 0, stream>>>(S0h, S0l, WdH, WdL, nullptr, nullptr,
                                                 A1, nullptr, nullptr, DM);
    wsplit_k<<<dim3(16,16), dim3(256), 0, stream>>>(Wv, WdH, WdL, DM, DM);
    gemm_s<<<dim3(4,49), dim3(256), 0, stream>>>(S0h, S0l, WdH, WdL, nullptr, nullptr,
                                                 A2, nullptr, nullptr, DM);
    // attention -> split S1
    fattn_k<<<dim3(4,256), dim3(256), 0, stream>>>(A0, A1, A2, S1h, S1l);
    // output projection: S1 -> A0 fp32 (router + MoE input)
    wsplit_k<<<dim3(16,16), dim3(256), 0, stream>>>(Wo, WdH, WdL, DM, DM);
    gemm_s<<<dim3(4,49), dim3(256), 0, stream>>>(S1h, S1l, WdH, WdL, bo, nullptr,
                                                 A0, nullptr, nullptr, DM);
    // expert weights -> bf16 transposed
    transconv_k<<<dim3(FFD/32, DM/32, NE), dim3(256), 0, stream>>>(eWi, WiT, DM, FFD);
    transconv_k<<<dim3(DM/32, FFD/32, NE), dim3(256), 0, stream>>>(eWo, WoT, FFD, DM);
    // routing
    router2_k<<<dim3(BT/4), dim3(256), 0, stream>>>(A0, rtW, rtb, rnW, rnb, nz, tok_e, tok_g);
    route_assign_k<<<dim3(1), dim3(1024), 0, stream>>>(tok_e, offs, idx_c, tok_slot);
    gatherconv_k<<<dim3(SLOTS), dim3(256), 0, stream>>>(A0, idx_c, Xg);
    // experts
    for (int c0 = 0; c0 < FFD; c0 += fcw){
      moe_mfma<0><<<dim3(fcw/128, 49, NE), dim3(256), 0, stream>>>(
          Xg, WiT + (size_t)c0*DM, ebi + c0, offs, (void*)H1b, DM, DM, fcw, 0);
      moe_mfma<1><<<dim3(DM/128, 49, NE), dim3(256), 0, stream>>>(
          H1b, WoT + c0, ebo, offs, (void*)Yexp, fcw, FFD, DM, c0);
    }
    // combine + LN -> split S0
    combine_ln_k<<<dim3(BT), dim3(256), 0, stream>>>(Yexp, tok_slot, tok_g, lng, lnb, S0h, S0l);
    // vector projection: S0 -> out mirror (fp32) + split S1 (next layer input)
    gemm_s<<<dim3(4,49), dim3(256), 0, stream>>>(S0h, S0l, VecH, VecL, vecB, nullptr,
                                                 out + (size_t)l*ABUF, S1h, S1l, DM);
  }

  gsum_k<<<dim3(64), dim3(256), 0, stream>>>(out + ABUF, gbv, out + 2*ABUF);
  gemm_f32<<<dim3(8,1), dim3(256), 0, stream>>>(gbv, clsW, clsbuf, clsB, out + 2*ABUF + 16384, 32, DM, DM);
}

// Round 3
// 1066.711 us; speedup vs baseline: 2.7384x; 1.1520x over previous
//
#include <hip/hip_runtime.h>

#define BT 6272      // B*T = 32*196
#define TT 196
#define DM 512
#define FFD 2048
#define NE 8
#define ABUF 3211264 // activation buffer elems (6272*512)
#define SLOTS 12544  // BT*2 expert slots

typedef float f32x4 __attribute__((ext_vector_type(4)));
typedef __bf16 bf16x8 __attribute__((ext_vector_type(8)));

__device__ __forceinline__ ushort f2bf(float f){
  union { float f; unsigned u; } v; v.f = f;
  unsigned u = v.u;
  u += 0x7fffu + ((u >> 16) & 1u);   // RNE
  return (ushort)(u >> 16);
}
__device__ __forceinline__ float bf2f(ushort u){
  union { unsigned u; float f; } c; c.u = ((unsigned)u) << 16; return c.f;
}
// split fp32 into bf16 hi (truncated) + bf16 lo (RNE of remainder): a ~= hi + lo, err ~2^-17
__device__ __forceinline__ void splitbf(float v, ushort& hi, ushort& lo){
  union { float f; unsigned u; } c; c.f = v;
  hi = (ushort)(c.u >> 16);
  union { unsigned u; float f; } hf; hf.u = c.u & 0xffff0000u;
  lo = f2bf(v - hf.f);
}

// ---------------- patchify: x[B,1,224,224] f32 -> split-bf16 patches[BT,256] ----------------
__global__ void patchify_k(const float* __restrict__ x, ushort* __restrict__ oh, ushort* __restrict__ ol){
  int bt = blockIdx.x;
  int t = bt % TT, b = bt / TT;
  int pd = threadIdx.x;
  int g1 = t / 14, g2 = t % 14, p1 = pd >> 4, p2 = pd & 15;
  int src = (b*224 + g1*16 + p1)*224 + g2*16 + p2;
  float v = x[src];
  ushort hu, lu; splitbf(v, hu, lu);
  oh[(size_t)bt*256 + pd] = hu;
  ol[(size_t)bt*256 + pd] = lu;
}

// ---------------- posenc[196,512] f32 ----------------
__global__ void posenc_k(float* __restrict__ pe){
  int t = blockIdx.x, c = threadIdx.x;
  int m2 = c & ~1;
  double ang = (double)t * pow(10000.0, -(double)m2 / 512.0);
  double vv = (c & 1) ? cos(ang) : sin(ang);
  pe[t*DM + c] = (float)vv;
}

// ---------------- weight transpose + split: src[R][C] f32 -> dh/dl[C][R] bf16 hi/lo ----------------
__global__ __launch_bounds__(256)
void wsplit_k(const float* __restrict__ src, ushort* __restrict__ dh, ushort* __restrict__ dl,
              int R, int C){
  __shared__ float t[32][33];
  int c0 = blockIdx.x << 5, r0 = blockIdx.y << 5;
  int tx = threadIdx.x & 31, ty = threadIdx.x >> 5;
  #pragma unroll
  for (int i = 0; i < 32; i += 8)
    t[ty+i][tx] = src[(size_t)(r0+ty+i)*C + c0 + tx];
  __syncthreads();
  #pragma unroll
  for (int i = 0; i < 32; i += 8){
    float v = t[tx][ty+i];
    ushort hu, lu; splitbf(v, hu, lu);
    dh[(size_t)(c0+ty+i)*R + r0 + tx] = hu;
    dl[(size_t)(c0+ty+i)*R + r0 + tx] = lu;
  }
}

// ---------------- batched 5-way 512x512 weight transpose+split (one launch per layer) --------
__global__ __launch_bounds__(256)
void wsplit5_k(const float* __restrict__ s0, const float* __restrict__ s1,
               const float* __restrict__ s2, const float* __restrict__ s3,
               const float* __restrict__ s4,
               ushort* __restrict__ dWdH, ushort* __restrict__ dWdL,
               ushort* __restrict__ dQkvH, ushort* __restrict__ dQkvL,
               ushort* __restrict__ dWoH, ushort* __restrict__ dWoL)
{
  int z = blockIdx.z;
  const float* src = (z==0)? s0 : (z==1)? s1 : (z==2)? s2 : (z==3)? s3 : s4;
  ushort* dh; ushort* dl;
  if (z == 0){ dh = dWdH; dl = dWdL; }
  else if (z == 4){ dh = dWoH; dl = dWoL; }
  else { dh = dQkvH + (size_t)(z-1)*DM*DM; dl = dQkvL + (size_t)(z-1)*DM*DM; }
  __shared__ float t[32][33];
  int c0 = blockIdx.x << 5, r0 = blockIdx.y << 5;
  int tx = threadIdx.x & 31, ty = threadIdx.x >> 5;
  #pragma unroll
  for (int i = 0; i < 32; i += 8)
    t[ty+i][tx] = src[(size_t)(r0+ty+i)*DM + c0 + tx];
  __syncthreads();
  #pragma unroll
  for (int i = 0; i < 32; i += 8){
    float v = t[tx][ty+i];
    ushort hu, lu; splitbf(v, hu, lu);
    dh[(size_t)(c0+ty+i)*DM + r0 + tx] = hu;
    dl[(size_t)(c0+ty+i)*DM + r0 + tx] = lu;
  }
}

// ---------------- dense split-bf16 MFMA GEMM, 128x128 tile, reg-prefetch ----------------
// A: split pair [M][kld] k-contig; B: split pair [N][kld] k-contig (pre-transposed weights).
// Outputs any of: Cf fp32, (Ch,Cl) split-bf16; row stride N. Optional bias[col], posenc add.
__global__ __launch_bounds__(256)
void gemm_s(const ushort* __restrict__ Ah, const ushort* __restrict__ Al,
            const ushort* __restrict__ Bh, const ushort* __restrict__ Bl,
            const float* __restrict__ bias, const float* __restrict__ pe,
            float* __restrict__ Cf, ushort* __restrict__ Ch, ushort* __restrict__ Cl,
            int N, int kld)
{
  __shared__ ushort Ahs[128][40];   // stride 40 sh = 80B: 16B-aligned rows, bank-uniform
  __shared__ ushort Als[128][40];
  __shared__ ushort Bhs[128][40];
  __shared__ ushort Bls[128][40];
  int tid = threadIdx.x;
  int row0 = blockIdx.y << 7, col0 = blockIdx.x << 7;
  int r = tid >> 1, h16 = (tid & 1) << 4;
  int lane = tid & 63, w = tid >> 6;
  int wr = w >> 1, wc = w & 1;
  const ushort* Aph = Ah + (size_t)(row0 + r) * kld + h16;
  const ushort* Apl = Al + (size_t)(row0 + r) * kld + h16;
  const ushort* Bph = Bh + (size_t)(col0 + r) * kld + h16;
  const ushort* Bpl = Bl + (size_t)(col0 + r) * kld + h16;
  uint4 pah0 = *(const uint4*)(Aph);
  uint4 pah1 = *(const uint4*)(Aph + 8);
  uint4 pal0 = *(const uint4*)(Apl);
  uint4 pal1 = *(const uint4*)(Apl + 8);
  uint4 pbh0 = *(const uint4*)(Bph);
  uint4 pbh1 = *(const uint4*)(Bph + 8);
  uint4 pbl0 = *(const uint4*)(Bpl);
  uint4 pbl1 = *(const uint4*)(Bpl + 8);
  f32x4 acc[4][4] = {};
  int fr = lane & 15, ksel = (lane >> 4) << 3;
  for (int k0 = 32; ; k0 += 32){
    __syncthreads();
    *(uint4*)&Ahs[r][h16]   = pah0;
    *(uint4*)&Ahs[r][h16+8] = pah1;
    *(uint4*)&Als[r][h16]   = pal0;
    *(uint4*)&Als[r][h16+8] = pal1;
    *(uint4*)&Bhs[r][h16]   = pbh0;
    *(uint4*)&Bhs[r][h16+8] = pbh1;
    *(uint4*)&Bls[r][h16]   = pbl0;
    *(uint4*)&Bls[r][h16+8] = pbl1;
    __syncthreads();
    if (k0 < kld){
      pah0 = *(const uint4*)(Aph + k0);
      pah1 = *(const uint4*)(Aph + k0 + 8);
      pal0 = *(const uint4*)(Apl + k0);
      pal1 = *(const uint4*)(Apl + k0 + 8);
      pbh0 = *(const uint4*)(Bph + k0);
      pbh1 = *(const uint4*)(Bph + k0 + 8);
      pbl0 = *(const uint4*)(Bpl + k0);
      pbl1 = *(const uint4*)(Bpl + k0 + 8);
    }
    bf16x8 ah[4], al[4];
    #pragma unroll
    for (int i = 0; i < 4; ++i){
      ah[i] = *(const bf16x8*)&Ahs[(wr<<6) + (i<<4) + fr][ksel];
      al[i] = *(const bf16x8*)&Als[(wr<<6) + (i<<4) + fr][ksel];
    }
    #pragma unroll
    for (int j = 0; j < 4; ++j){
      bf16x8 bh = *(const bf16x8*)&Bhs[(wc<<6) + (j<<4) + fr][ksel];
      bf16x8 bl = *(const bf16x8*)&Bls[(wc<<6) + (j<<4) + fr][ksel];
      #pragma unroll
      for (int i = 0; i < 4; ++i){
        acc[i][j] = __builtin_amdgcn_mfma_f32_16x16x32_bf16(ah[i], bh, acc[i][j], 0, 0, 0);
        acc[i][j] = __builtin_amdgcn_mfma_f32_16x16x32_bf16(al[i], bh, acc[i][j], 0, 0, 0);
        acc[i][j] = __builtin_amdgcn_mfma_f32_16x16x32_bf16(ah[i], bl, acc[i][j], 0, 0, 0);
      }
    }
    if (k0 >= kld) break;
  }
  int fq = lane >> 4;
  #pragma unroll
  for (int j = 0; j < 4; ++j){
    int col = col0 + (wc<<6) + (j<<4) + fr;
    float bv = bias ? bias[col] : 0.f;
    #pragma unroll
    for (int i = 0; i < 4; ++i){
      #pragma unroll
      for (int q = 0; q < 4; ++q){
        int rr = row0 + (wr<<6) + (i<<4) + (fq<<2) + q;
        float v = acc[i][j][q] + bv;
        if (pe) v += pe[(size_t)(rr % TT)*DM + col];
        size_t off = (size_t)rr*N + col;
        if (Cf) Cf[off] = v;
        if (Ch){
          ushort hu, lu; splitbf(v, hu, lu);
          Ch[off] = hu; Cl[off] = lu;
        }
      }
    }
  }
}

// ---------------- old 64x64 GEMM (kept for the tiny cls matmul, M=32) ----------------
__global__ __launch_bounds__(256)
void gemm_f32(const float* __restrict__ A, const float* __restrict__ Bw,
              float* __restrict__ C, const float* __restrict__ bias,
              float* __restrict__ obf, int M, int N, int K)
{
  __shared__ float As[16][68];
  __shared__ float Bs[16][68];
  int tid = threadIdx.x;
  int row0 = blockIdx.y << 6, col0 = blockIdx.x << 6;
  int ar = tid >> 2, ak = (tid & 3) << 2;
  int bk = tid >> 4, bn = (tid & 15) << 2;
  int n0 = (tid & 15) << 2, m0 = (tid >> 4) << 2;
  float acc[4][4] = {};
  bool arow_ok = (row0 + ar) < M;
  const float* Aldg = A + (size_t)(row0 + ar) * K + ak;
  const float* Bldg = Bw + (size_t)bk * N + col0 + bn;
  for (int k0 = 0; k0 < K; k0 += 16){
    float4 av = make_float4(0.f,0.f,0.f,0.f);
    if (arow_ok) av = *(const float4*)(Aldg + k0);
    float4 bv = *(const float4*)(Bldg + (size_t)k0 * N);
    __syncthreads();
    As[ak+0][ar]=av.x; As[ak+1][ar]=av.y; As[ak+2][ar]=av.z; As[ak+3][ar]=av.w;
    *(float4*)&Bs[bk][bn] = bv;
    __syncthreads();
    #pragma unroll
    for (int kk = 0; kk < 16; ++kk){
      float4 a = *(const float4*)&As[kk][m0];
      float4 b = *(const float4*)&Bs[kk][n0];
      float aa[4] = {a.x,a.y,a.z,a.w};
      float bb[4] = {b.x,b.y,b.z,b.w};
      #pragma unroll
      for (int i = 0; i < 4; ++i)
        #pragma unroll
        for (int j = 0; j < 4; ++j)
          acc[i][j] += aa[i]*bb[j];
    }
  }
  float4 badd = make_float4(0.f,0.f,0.f,0.f);
  if (bias) badd = *(const float4*)(bias + col0 + n0);
  #pragma unroll
  for (int i = 0; i < 4; ++i){
    int gr = row0 + m0 + i;
    if (gr < M){
      float4 r = make_float4(acc[i][0]+badd.x, acc[i][1]+badd.y, acc[i][2]+badd.z, acc[i][3]+badd.w);
      *(float4*)(C + (size_t)gr*N + col0 + n0) = r;
      if (obf) *(float4*)(obf + (size_t)gr*N + col0 + n0) = r;
    }
  }
}

// ---------------- MFMA flash attention (split-bf16 QK^T and PV, fp32 softmax) ----------------
// X layout: [BT][1536] split pair: q at +0, k at +512, v at +1024; head slice h*64.
// Output: split pair [BT][512].
__global__ __launch_bounds__(256)
void fattn_k(const ushort* __restrict__ Xh, const ushort* __restrict__ Xl,
             ushort* __restrict__ oh, ushort* __restrict__ ol)
{
  __shared__ ushort Kh[64][72], Kl[64][72];    // stride 72 sh = 144B (16B-aligned)
  __shared__ ushort Vth[64][72], Vtl[64][72];  // V transposed: [d][key]
  __shared__ ushort Ph[64][72], Pl[64][72];    // P split, wave-local stripes
  int qt = blockIdx.x, bh = blockIdx.y;
  int b = bh >> 3, h = bh & 7;
  int tid = threadIdx.x;
  int w = tid >> 6, lane = tid & 63;
  int fr = lane & 15, fu = lane >> 4;
  // Q fragments (A-operand rows = lane&15) direct from global, kept in registers
  int qrow_f = qt*64 + w*16 + fr;
  int qtok = b*TT + (qrow_f < TT ? qrow_f : TT-1);
  const ushort* qph = Xh + (size_t)qtok*1536 + h*64 + fu*8;
  const ushort* qpl = Xl + (size_t)qtok*1536 + h*64 + fu*8;
  bf16x8 qh0 = *(const bf16x8*)(qph);
  bf16x8 qh1 = *(const bf16x8*)(qph + 32);
  bf16x8 ql0 = *(const bf16x8*)(qpl);
  bf16x8 ql1 = *(const bf16x8*)(qpl + 32);
  f32x4 o_acc[4] = {};
  float m_i[4], l_i[4];
  #pragma unroll
  for (int q = 0; q < 4; ++q){ m_i[q] = -3e38f; l_i[q] = 0.f; }
  int sr = tid >> 2, sc = (tid & 3) << 4;   // staging: row sr, 16-short chunk sc
  int ktiles = qt + 1;
  for (int kt = 0; kt < ktiles; ++kt){
    __syncthreads();
    {
      int jrow = kt*64 + sr;
      int jtok = b*TT + (jrow < TT ? jrow : TT-1);
      const ushort* kph = Xh + (size_t)jtok*1536 + 512 + h*64 + sc;
      const ushort* kpl = Xl + (size_t)jtok*1536 + 512 + h*64 + sc;
      *(uint4*)&Kh[sr][sc]   = *(const uint4*)kph;
      *(uint4*)&Kh[sr][sc+8] = *(const uint4*)(kph + 8);
      *(uint4*)&Kl[sr][sc]   = *(const uint4*)kpl;
      *(uint4*)&Kl[sr][sc+8] = *(const uint4*)(kpl + 8);
      const ushort* vph = Xh + (size_t)jtok*1536 + 1024 + h*64 + sc;
      const ushort* vpl = Xl + (size_t)jtok*1536 + 1024 + h*64 + sc;
      ushort tv[16];
      *(uint4*)&tv[0] = *(const uint4*)vph;
      *(uint4*)&tv[8] = *(const uint4*)(vph + 8);
      #pragma unroll
      for (int t = 0; t < 16; ++t) Vth[sc + t][sr] = tv[t];
      *(uint4*)&tv[0] = *(const uint4*)vpl;
      *(uint4*)&tv[8] = *(const uint4*)(vpl + 8);
      #pragma unroll
      for (int t = 0; t < 16; ++t) Vtl[sc + t][sr] = tv[t];
    }
    __syncthreads();
    // S = Q K^T (3-term split)
    f32x4 sacc[4] = {};
    #pragma unroll
    for (int j = 0; j < 4; ++j){
      bf16x8 kh0 = *(const bf16x8*)&Kh[j*16 + fr][fu*8];
      bf16x8 kh1 = *(const bf16x8*)&Kh[j*16 + fr][32 + fu*8];
      bf16x8 kl0 = *(const bf16x8*)&Kl[j*16 + fr][fu*8];
      bf16x8 kl1 = *(const bf16x8*)&Kl[j*16 + fr][32 + fu*8];
      sacc[j] = __builtin_amdgcn_mfma_f32_16x16x32_bf16(qh0, kh0, sacc[j], 0, 0, 0);
      sacc[j] = __builtin_amdgcn_mfma_f32_16x16x32_bf16(ql0, kh0, sacc[j], 0, 0, 0);
      sacc[j] = __builtin_amdgcn_mfma_f32_16x16x32_bf16(qh0, kl0, sacc[j], 0, 0, 0);
      sacc[j] = __builtin_amdgcn_mfma_f32_16x16x32_bf16(qh1, kh1, sacc[j], 0, 0, 0);
      sacc[j] = __builtin_amdgcn_mfma_f32_16x16x32_bf16(ql1, kh1, sacc[j], 0, 0, 0);
      sacc[j] = __builtin_amdgcn_mfma_f32_16x16x32_bf16(qh1, kl1, sacc[j], 0, 0, 0);
    }
    // mask + scale + online softmax (C rows = fu*4+q, cols = j*16+fr)
    int rbase = qt*64 + w*16 + (fu<<2);
    int cg = kt*64 + fr;
    float p[4][4];
    #pragma unroll
    for (int q = 0; q < 4; ++q){
      int rg = rbase + q;
      float sv[4];
      #pragma unroll
      for (int j = 0; j < 4; ++j){
        int cj = cg + j*16;
        sv[j] = (cj <= rg && cj < TT) ? sacc[j][q]*0.125f : -3e38f;
      }
      float mx = fmaxf(fmaxf(sv[0],sv[1]), fmaxf(sv[2],sv[3]));
      #pragma unroll
      for (int off = 1; off < 16; off <<= 1) mx = fmaxf(mx, __shfl_xor(mx, off, 64));
      float mnew = fmaxf(m_i[q], mx);
      float al = expf(m_i[q] - mnew);
      l_i[q] *= al;
      o_acc[0][q] *= al; o_acc[1][q] *= al; o_acc[2][q] *= al; o_acc[3][q] *= al;
      float ps = 0.f;
      #pragma unroll
      for (int j = 0; j < 4; ++j){ p[q][j] = expf(sv[j] - mnew); ps += p[q][j]; }
      #pragma unroll
      for (int off = 1; off < 16; off <<= 1) ps += __shfl_xor(ps, off, 64);
      l_i[q] += ps;
      m_i[q] = mnew;
    }
    // P -> LDS (own wave stripe, split bf16); readback as A-fragments (wave-local RAW)
    #pragma unroll
    for (int q = 0; q < 4; ++q){
      int pr = w*16 + (fu<<2) + q;
      #pragma unroll
      for (int j = 0; j < 4; ++j){
        ushort hu, lu; splitbf(p[q][j], hu, lu);
        Ph[pr][j*16 + fr] = hu;
        Pl[pr][j*16 + fr] = lu;
      }
    }
    bf16x8 ph0 = *(const bf16x8*)&Ph[w*16 + fr][fu*8];
    bf16x8 ph1 = *(const bf16x8*)&Ph[w*16 + fr][32 + fu*8];
    bf16x8 pl0 = *(const bf16x8*)&Pl[w*16 + fr][fu*8];
    bf16x8 pl1 = *(const bf16x8*)&Pl[w*16 + fr][32 + fu*8];
    #pragma unroll
    for (int jd = 0; jd < 4; ++jd){
      bf16x8 vh0 = *(const bf16x8*)&Vth[jd*16 + fr][fu*8];
      bf16x8 vh1 = *(const bf16x8*)&Vth[jd*16 + fr][32 + fu*8];
      bf16x8 vl0 = *(const bf16x8*)&Vtl[jd*16 + fr][fu*8];
      bf16x8 vl1 = *(const bf16x8*)&Vtl[jd*16 + fr][32 + fu*8];
      o_acc[jd] = __builtin_amdgcn_mfma_f32_16x16x32_bf16(ph0, vh0, o_acc[jd], 0, 0, 0);
      o_acc[jd] = __builtin_amdgcn_mfma_f32_16x16x32_bf16(pl0, vh0, o_acc[jd], 0, 0, 0);
      o_acc[jd] = __builtin_amdgcn_mfma_f32_16x16x32_bf16(ph0, vl0, o_acc[jd], 0, 0, 0);
      o_acc[jd] = __builtin_amdgcn_mfma_f32_16x16x32_bf16(ph1, vh1, o_acc[jd], 0, 0, 0);
      o_acc[jd] = __builtin_amdgcn_mfma_f32_16x16x32_bf16(pl1, vh1, o_acc[jd], 0, 0, 0);
      o_acc[jd] = __builtin_amdgcn_mfma_f32_16x16x32_bf16(ph1, vl1, o_acc[jd], 0, 0, 0);
    }
  }
  #pragma unroll
  for (int q = 0; q < 4; ++q){
    int rg = qt*64 + w*16 + (fu<<2) + q;
    if (rg < TT){
      float inv = 1.f / l_i[q];
      size_t rowoff = (size_t)(b*TT + rg)*DM + h*64 + fr;
      #pragma unroll
      for (int jd = 0; jd < 4; ++jd){
        float v = o_acc[jd][q] * inv;
        ushort hu, lu; splitbf(v, hu, lu);
        oh[rowoff + jd*16] = hu;
        ol[rowoff + jd*16] = lu;
      }
    }
  }
}

// ---------------- router: reads split-bf16 X pair; LDS-staged transposed weights ----------------
__global__ __launch_bounds__(256)
void router2_k(const ushort* __restrict__ Xh, const ushort* __restrict__ Xl,
               const float* __restrict__ rtW, const float* __restrict__ rtb,
               const float* __restrict__ rnW, const float* __restrict__ rnb, const float* __restrict__ nz,
               int* __restrict__ tok_e, float* __restrict__ tok_g)
{
  __shared__ float Wt[8*513];
  __shared__ float Wn[8*513];
  int tid = threadIdx.x;
  for (int i = tid*4; i < DM*8; i += 1024){
    float4 t = *(const float4*)(rtW + i);
    float4 n = *(const float4*)(rnW + i);
    int d = i >> 3, e = i & 7;
    Wt[(e+0)*513 + d] = t.x; Wt[(e+1)*513 + d] = t.y; Wt[(e+2)*513 + d] = t.z; Wt[(e+3)*513 + d] = t.w;
    Wn[(e+0)*513 + d] = n.x; Wn[(e+1)*513 + d] = n.y; Wn[(e+2)*513 + d] = n.z; Wn[(e+3)*513 + d] = n.w;
  }
  __syncthreads();
  int w = tid >> 6, lane = tid & 63;
  int t = (blockIdx.x << 2) + w;
  const ushort* xh = Xh + (size_t)t * DM;
  const ushort* xl = Xl + (size_t)t * DM;
  float at[8] = {}, an[8] = {};
  #pragma unroll
  for (int u = 0; u < 8; ++u){
    int d = (u<<6) + lane;
    float xv = bf2f(xh[d]) + bf2f(xl[d]);
    #pragma unroll
    for (int e = 0; e < 8; ++e){
      at[e] += xv * Wt[e*513 + d];
      an[e] += xv * Wn[e*513 + d];
    }
  }
  #pragma unroll
  for (int off = 32; off; off >>= 1){
    #pragma unroll
    for (int e = 0; e < 8; ++e){
      at[e] += __shfl_xor(at[e], off, 64);
      an[e] += __shfl_xor(an[e], off, 64);
    }
  }
  if (lane == 0){
    float ns[8];
    #pragma unroll
    for (int e = 0; e < 8; ++e){
      float lt = at[e] + rtb[e];
      float ln_ = an[e] + rnb[e];
      float sp = (ln_ > 0.f) ? (ln_ + log1pf(expf(-ln_))) : log1pf(expf(ln_));
      ns[e] = lt + nz[(size_t)t*8 + e] * sp;
    }
    int i1 = 0; float n1 = ns[0];
    #pragma unroll
    for (int e = 1; e < 8; ++e) if (ns[e] > n1){ n1 = ns[e]; i1 = e; }
    int i2 = -1; float n2 = -3e38f;
    #pragma unroll
    for (int e = 0; e < 8; ++e) if (e != i1 && ns[e] > n2){ n2 = ns[e]; i2 = e; }
    float ex = expf(n2 - n1);
    float inv = 1.f / (1.f + ex);
    tok_e[t*2]   = i1; tok_g[t*2]   = inv;
    tok_e[t*2+1] = i2; tok_g[t*2+1] = ex * inv;
  }
}

// ---------------- single-block histogram + prefix + slot assignment ----------------
__global__ __launch_bounds__(1024)
void route_assign_k(const int* __restrict__ tok_e, int* __restrict__ offs_g,
                    int* __restrict__ idx_c, int* __restrict__ tok_slot)
{
  __shared__ int hist[NE];
  __shared__ int cur[NE];
  int tid = threadIdx.x;
  if (tid < NE) hist[tid] = 0;
  __syncthreads();
  for (int i = tid; i < BT*2; i += 1024) atomicAdd(&hist[tok_e[i]], 1);
  __syncthreads();
  if (tid == 0){
    int s = 0;
    for (int e = 0; e < NE; ++e){ offs_g[e] = s; cur[e] = s; s += hist[e]; }
    offs_g[NE] = s;
  }
  __syncthreads();
  for (int i = tid; i < BT*2; i += 1024){
    int e = tok_e[i];
    int p = atomicAdd(&cur[e], 1);
    idx_c[p] = i >> 1;
    tok_slot[i] = p;
  }
}

// ---------------- transpose + f32->bf16 convert (expert weights): src[R][C] -> dst[C][R] ----------------
__global__ __launch_bounds__(256)
void transconv_k(const float* __restrict__ src, ushort* __restrict__ dst, int R, int C){
  __shared__ float t[32][33];
  int e = blockIdx.z;
  src += (size_t)e * R * C;
  dst += (size_t)e * R * C;
  int c0 = blockIdx.x << 5, r0 = blockIdx.y << 5;
  int tx = threadIdx.x & 31, ty = threadIdx.x >> 5;
  #pragma unroll
  for (int i = 0; i < 32; i += 8)
    t[ty+i][tx] = src[(size_t)(r0+ty+i)*C + c0 + tx];
  __syncthreads();
  #pragma unroll
  for (int i = 0; i < 32; i += 8)
    dst[(size_t)(c0+ty+i)*R + r0 + tx] = f2bf(t[tx][ty+i]);
}

// ---------------- gather routed rows (bf16 hi): Xg[slot][512] ----------------
__global__ void gatherconv_k(const ushort* __restrict__ Xh, const int* __restrict__ idx,
                             ushort* __restrict__ Xg){
  int s = blockIdx.x;
  const ushort* xp = Xh + (size_t)idx[s] * DM;
  ushort* op = Xg + (size_t)s * DM;
  int i = threadIdx.x * 2;
  *(ushort2*)(op + i) = *(const ushort2*)(xp + i);
}

// ---------------- MoE expert GEMM, bf16 MFMA 16x16x32, 128x128 tile, 4 waves ----------------
template<int MODE>
__global__ __launch_bounds__(256)
void moe_mfma(const ushort* __restrict__ A, const ushort* __restrict__ Bt,
              const float* __restrict__ bias, const int* __restrict__ offs,
              void* __restrict__ Out, int kld, int ldb, int out_ld, int accum)
{
  int e = blockIdx.z;
  int base = offs[e], cnt = offs[e+1] - base;
  int row0 = blockIdx.y << 7;
  if (row0 >= cnt) return;
  int col0 = blockIdx.x << 7;
  __shared__ ushort As[128][40];
  __shared__ ushort Bs[128][40];
  int tid = threadIdx.x;
  int r = tid >> 1, h = (tid & 1) << 4;
  int lane = tid & 63, w = tid >> 6;
  int wr = w >> 1, wc = w & 1;
  int sidx = base + row0 + r; if (sidx > SLOTS-1) sidx = SLOTS-1;
  const ushort* Ap = A + (size_t)sidx * kld + h;
  const ushort* Bp = Bt + (size_t)e * ((size_t)FFD*DM) + (size_t)(col0 + r) * ldb + h;
  uint4 pa0 = *(const uint4*)Ap;
  uint4 pa1 = *(const uint4*)(Ap + 8);
  uint4 pb0 = *(const uint4*)Bp;
  uint4 pb1 = *(const uint4*)(Bp + 8);
  f32x4 acc[4][4] = {};
  int fr = lane & 15, ksel = (lane >> 4) << 3;
  int k0 = 0;
  while (true){
    __syncthreads();
    *(uint4*)&As[r][h]     = pa0;
    *(uint4*)&As[r][h + 8] = pa1;
    *(uint4*)&Bs[r][h]     = pb0;
    *(uint4*)&Bs[r][h + 8] = pb1;
    __syncthreads();
    k0 += 32;
    if (k0 < kld){
      pa0 = *(const uint4*)(Ap + k0);
      pa1 = *(const uint4*)(Ap + k0 + 8);
      pb0 = *(const uint4*)(Bp + k0);
      pb1 = *(const uint4*)(Bp + k0 + 8);
    }
    bf16x8 af[4], bf[4];
    #pragma unroll
    for (int i = 0; i < 4; ++i){
      af[i] = *(const bf16x8*)&As[(wr<<6) + (i<<4) + fr][ksel];
      bf[i] = *(const bf16x8*)&Bs[(wc<<6) + (i<<4) + fr][ksel];
    }
    #pragma unroll
    for (int i = 0; i < 4; ++i)
      #pragma unroll
      for (int j = 0; j < 4; ++j)
        acc[i][j] = __builtin_amdgcn_mfma_f32_16x16x32_bf16(af[i], bf[j], acc[i][j], 0, 0, 0);
    if (k0 >= kld) break;
  }
  int fq = lane >> 4;
  #pragma unroll
  for (int j = 0; j < 4; ++j){
    int col = col0 + (wc<<6) + (j<<4) + fr;
    float bv = bias[(size_t)e * ((MODE==0)?FFD:DM) + col];
    #pragma unroll
    for (int i = 0; i < 4; ++i){
      #pragma unroll
      for (int q = 0; q < 4; ++q){
        int rr = row0 + (wr<<6) + (i<<4) + (fq<<2) + q;
        if (rr < cnt){
          if (MODE == 0){
            float vv = acc[i][j][q] + bv;
            ((ushort*)Out)[(size_t)(base+rr)*out_ld + col] = f2bf(fmaxf(vv, 0.f));
          } else {
            float* yp = (float*)Out + (size_t)(base+rr)*out_ld + col;
            *yp = acc[i][j][q] + (accum ? *yp : bv);
          }
        }
      }
    }
  }
}

// ---------------- gated combine + layernorm; output as split-bf16 ----------------
__global__ __launch_bounds__(256)
void combine_ln_k(const float* __restrict__ Ye, const int* __restrict__ tok_slot,
                  const float* __restrict__ tok_g, const float* __restrict__ g,
                  const float* __restrict__ bb, ushort* __restrict__ oh, ushort* __restrict__ ol)
{
  int t = blockIdx.x, tid = threadIdx.x;
  int s1 = tok_slot[t*2], s2 = tok_slot[t*2+1];
  float g1 = tok_g[t*2], g2 = tok_g[t*2+1];
  const float* y1 = Ye + (size_t)s1*DM;
  const float* y2 = Ye + (size_t)s2*DM;
  float v0 = g1*y1[tid]     + g2*y2[tid];
  float v1 = g1*y1[tid+256] + g2*y2[tid+256];
  __shared__ float red[8];
  int w = tid >> 6, lane = tid & 63;
  float s = v0 + v1;
  #pragma unroll
  for (int off = 32; off; off >>= 1) s += __shfl_xor(s, off, 64);
  if (lane == 0) red[w] = s;
  __syncthreads();
  float mu = (red[0]+red[1]+red[2]+red[3]) * (1.f/512.f);
  float d0 = v0 - mu, d1 = v1 - mu;
  float q2 = d0*d0 + d1*d1;
  #pragma unroll
  for (int off = 32; off; off >>= 1) q2 += __shfl_xor(q2, off, 64);
  if (lane == 0) red[4+w] = q2;
  __syncthreads();
  float var = (red[4]+red[5]+red[6]+red[7]) * (1.f/512.f);
  float r = 1.f / sqrtf(var + 1e-5f);
  float r0v = d0*r*g[tid]     + bb[tid];
  float r1v = d1*r*g[tid+256] + bb[tid+256];
  ushort hu, lu;
  splitbf(r0v, hu, lu);
  oh[(size_t)t*DM + tid] = hu; ol[(size_t)t*DM + tid] = lu;
  splitbf(r1v, hu, lu);
  oh[(size_t)t*DM + tid + 256] = hu; ol[(size_t)t*DM + tid + 256] = lu;
}

// ---------------- global = sum over T of second_vector ----------------
__global__ void gsum_k(const float* __restrict__ sv, float* __restrict__ gb, float* __restrict__ gout){
  int i = blockIdx.x*256 + threadIdx.x;
  int b = i >> 9, d = i & 511;
  const float* p = sv + (size_t)b*TT*DM + d;
  float s = 0.f;
  for (int t = 0; t < TT; ++t) s += p[(size_t)t*DM];
  gb[i] = s; gout[i] = s;
}

extern "C" void kernel_launch(void* const* d_in, const int* in_sizes, int n_in,
                              void* d_out, int out_size, void* d_ws, size_t ws_size,
                              hipStream_t stream)
{
  (void)in_sizes; (void)n_in; (void)out_size;
  const float* xin   = (const float*)d_in[0];
  const float* pembW = (const float*)d_in[1];
  const float* pembB = (const float*)d_in[2];
  const float* vecW  = (const float*)d_in[3];
  const float* vecB  = (const float*)d_in[4];
  const float* clsW  = (const float*)d_in[5];
  const float* clsB  = (const float*)d_in[6];
  float* out = (float*)d_out;

  // ---- workspace budget (floats) ----
  const size_t QKV_SH = (size_t)2 * BT * 1536;         // split QKV pair, shorts
  const size_t BASEF =
      (size_t)SLOTS*DM                                  // Yexp fp32
    + (size_t)2*ABUF                                    // S0/S1 split pairs (4*ABUF shorts)
    + (size_t)SLOTS*DM/2                                // Xg shorts
    + (size_t)NE*FFD*DM                                 // WiT+WoT shorts
    + (2*256*DM + 2*DM*DM + 2*3*DM*DM + 2*DM*DM + 2*DM*DM)/2  // weight split pairs
    + (size_t)TT*DM                                     // posenc
    + 16384*2 + SLOTS + SLOTS*3 + 64;
  int fcw = 1024;
  for (int cand = 2048; cand >= 256; cand >>= 1){
    size_t reg_sh = (size_t)SLOTS*cand > QKV_SH ? (size_t)SLOTS*cand : QKV_SH;
    size_t need = (BASEF + reg_sh/2) * sizeof(float);
    if (need <= ws_size){ fcw = cand; break; }
  }
  size_t region_sh = (size_t)SLOTS*fcw > QKV_SH ? (size_t)SLOTS*fcw : QKV_SH;

  float* ws = (float*)d_ws;
  float* Yexp = ws;                                     // SLOTS*DM fp32
  ushort* S0h = (ushort*)(Yexp + (size_t)SLOTS*DM);
  ushort* S0l = S0h + ABUF;
  ushort* S1h = S0l + ABUF;
  ushort* S1l = S1h + ABUF;
  ushort* region = S1l + ABUF;                          // H1b / QKV / patches alias
  ushort* Xg   = region + region_sh;
  ushort* WiT  = Xg + (size_t)SLOTS*DM;
  ushort* WoT  = WiT + (size_t)NE*FFD*DM;
  ushort* PembH = WoT + (size_t)NE*FFD*DM;
  ushort* PembL = PembH + 256*DM;
  ushort* VecH = PembL + 256*DM;
  ushort* VecL = VecH + DM*DM;
  ushort* QkvWH = VecL + DM*DM;
  ushort* QkvWL = QkvWH + 3*DM*DM;
  ushort* WoSH = QkvWL + 3*DM*DM;
  ushort* WoSL = WoSH + DM*DM;
  ushort* WdH  = WoSL + DM*DM;
  ushort* WdL  = WdH + DM*DM;
  float* pe    = (float*)(WdL + DM*DM);
  float* gbv   = pe + TT*DM;
  float* clsbuf= gbv + 16384;
  float* tok_g = clsbuf + 16384;
  int* tok_e   = (int*)(tok_g + SLOTS);
  int* tok_slot= tok_e + SLOTS;
  int* idx_c   = tok_slot + SLOTS;
  int* offs    = idx_c + SLOTS;
  ushort* QKVh = region;
  ushort* QKVl = region + (size_t)BT*1536;
  ushort* H1b  = region;
  ushort* PATh = region;                                // patches pair (dead before QKV)
  ushort* PATl = region + (size_t)BT*256;

  patchify_k<<<dim3(BT), dim3(256), 0, stream>>>(xin, PATh, PATl);
  posenc_k<<<dim3(TT), dim3(512), 0, stream>>>(pe);
  wsplit_k<<<dim3(16, 8), dim3(256), 0, stream>>>(pembW, PembH, PembL, 256, DM);
  wsplit_k<<<dim3(16, 16), dim3(256), 0, stream>>>(vecW, VecH, VecL, DM, DM);
  // h = patches @ pembW + b + posenc -> split S0
  gemm_s<<<dim3(4,49), dim3(256), 0, stream>>>(PATh, PATl, PembH, PembL, pembB, pe,
                                               nullptr, S0h, S0l, DM, 256);

  ushort *INh = S0h, *INl = S0l, *TPh = S1h, *TPl = S1l;
  for (int l = 0; l < 2; ++l){
    int base = 7 + 18*l;
    const float* pW  = (const float*)d_in[base+0];
    const float* pb  = (const float*)d_in[base+1];
    const float* Wq  = (const float*)d_in[base+2];
    const float* Wk  = (const float*)d_in[base+3];
    const float* Wv  = (const float*)d_in[base+4];
    const float* Wo  = (const float*)d_in[base+5];
    const float* bo  = (const float*)d_in[base+6];
    const float* rtW = (const float*)d_in[base+7];
    const float* rtb = (const float*)d_in[base+8];
    const float* rnW = (const float*)d_in[base+9];
    const float* rnb = (const float*)d_in[base+10];
    const float* eWi = (const float*)d_in[base+11];
    const float* ebi = (const float*)d_in[base+12];
    const float* eWo = (const float*)d_in[base+13];
    const float* ebo = (const float*)d_in[base+14];
    const float* lng = (const float*)d_in[base+15];
    const float* lnb = (const float*)d_in[base+16];
    const float* nz  = (const float*)d_in[base+17];

    // all dense weights for this layer in one launch
    wsplit5_k<<<dim3(16,16,5), dim3(256), 0, stream>>>(pW, Wq, Wk, Wv, Wo,
                                                       WdH, WdL, QkvWH, QkvWL, WoSH, WoSL);
    // input projection: IN -> TP
    gemm_s<<<dim3(4,49), dim3(256), 0, stream>>>(INh, INl, WdH, WdL, pb, nullptr,
                                                 nullptr, TPh, TPl, DM, DM);
    // fused QKV: TP -> QKV pair [BT][1536]
    gemm_s<<<dim3(12,49), dim3(256), 0, stream>>>(TPh, TPl, QkvWH, QkvWL, nullptr, nullptr,
                                                 nullptr, QKVh, QKVl, 1536, DM);
    // attention: QKV -> IN (split)
    fattn_k<<<dim3(4,256), dim3(256), 0, stream>>>(QKVh, QKVl, INh, INl);
    // output projection: IN -> TP (split X = router + MoE input)
    gemm_s<<<dim3(4,49), dim3(256), 0, stream>>>(INh, INl, WoSH, WoSL, bo, nullptr,
                                                 nullptr, TPh, TPl, DM, DM);
    // expert weights -> bf16 transposed
    transconv_k<<<dim3(FFD/32, DM/32, NE), dim3(256), 0, stream>>>(eWi, WiT, DM, FFD);
    transconv_k<<<dim3(DM/32, FFD/32, NE), dim3(256), 0, stream>>>(eWo, WoT, FFD, DM);
    // routing
    router2_k<<<dim3(BT/4), dim3(256), 0, stream>>>(TPh, TPl, rtW, rtb, rnW, rnb, nz, tok_e, tok_g);
    route_assign_k<<<dim3(1), dim3(1024), 0, stream>>>(tok_e, offs, idx_c, tok_slot);
    gatherconv_k<<<dim3(SLOTS), dim3(256), 0, stream>>>(TPh, idx_c, Xg);
    // experts (QKV region is dead now; H1b aliases it)
    for (int c0 = 0; c0 < FFD; c0 += fcw){
      moe_mfma<0><<<dim3(fcw/128, 49, NE), dim3(256), 0, stream>>>(
          Xg, WiT + (size_t)c0*DM, ebi + c0, offs, (void*)H1b, DM, DM, fcw, 0);
      moe_mfma<1><<<dim3(DM/128, 49, NE), dim3(256), 0, stream>>>(
          H1b, WoT + c0, ebo, offs, (void*)Yexp, fcw, FFD, DM, c0);
    }
    // combine + LN -> IN (split)
    combine_ln_k<<<dim3(BT), dim3(256), 0, stream>>>(Yexp, tok_slot, tok_g, lng, lnb, INh, INl);
    // vector projection: IN -> out mirror (fp32) + TP (next layer input, split)
    gemm_s<<<dim3(4,49), dim3(256), 0, stream>>>(INh, INl, VecH, VecL, vecB, nullptr,
                                                 out + (size_t)l*ABUF, TPh, TPl, DM, DM);
    ushort* th = INh; INh = TPh; TPh = th;
    ushort* tl = INl; INl = TPl; TPl = tl;
  }

  gsum_k<<<dim3(64), dim3(256), 0, stream>>>(out + ABUF, gbv, out + 2*ABUF);
  gemm_f32<<<dim3(8,1), dim3(256), 0, stream>>>(gbv, clsW, clsbuf, clsB, out + 2*ABUF + 16384, 32, DM, DM);
}